// Round 5
// baseline (1713.538 us; speedup 1.0000x reference)
//
#include <hip/hip_runtime.h>
#include <hip/hip_bf16.h>
#include <math.h>

#define NN 100000
#define NE 1600000
#define FF 128
#define HH 64
#define CC 10
#define GG 128
#define BN_EPS 1e-5f

// bucketed-edge constants
#define BNODES 128              // nodes per bucket (dst>>7)
#define NB 782                  // ceil(NN/BNODES)
#define NSUB 8                  // sub-segments per bucket (XCD-round-robin heuristic)
#define BCAP 512                // capacity per (bucket,sub): mean 256, +16 sigma
#define SCAT_BLOCKS 2048        // pass-A grid (multiple of NSUB)

typedef short v8bf __attribute__((ext_vector_type(8)));
typedef float v4f  __attribute__((ext_vector_type(4)));

__device__ inline ushort f2b(float x) {
    __hip_bfloat16 h = __float2bfloat16(x);
    return *reinterpret_cast<ushort*>(&h);
}
__device__ inline float b2f(ushort u) {
    return __uint_as_float(((unsigned)u) << 16);
}

// ---------------- W [K][64] fp32 -> bf16 swizzled into MFMA B-fragment order ----------
template<int K>
__global__ __launch_bounds__(256) void w_swizzle(const float* __restrict__ Wl,
                                                 const float* __restrict__ Wr,
                                                 ushort* __restrict__ ol,
                                                 ushort* __restrict__ orr) {
    constexpr int T = (K / 32) * 4 * 64;
    const int t = blockIdx.x * 256 + threadIdx.x;
    if (t >= T) return;
    const int lane = t & 63, nt = (t >> 6) & 3, ks = t >> 8;
    const int m = lane & 15, quad = lane >> 4;
#pragma unroll
    for (int j = 0; j < 8; ++j) {
        const int kk = ks * 32 + quad * 8 + j;
        const int cc = nt * 16 + m;
        ol[t * 8 + j]  = f2b(Wl[kk * 64 + cc]);
        orr[t * 8 + j] = f2b(Wr[kk * 64 + cc]);
    }
}

// ---------------- dual MFMA GEMM: Yl = X@Wl, Yr = X@Wr (bf16 out) ----------------
template<int K, int TPB, bool AF32>
__global__ __launch_bounds__(256) void gemm_mfma(const void* __restrict__ Xv,
                                                 const ushort* __restrict__ Bl,
                                                 const ushort* __restrict__ Br,
                                                 ushort* __restrict__ Yl,
                                                 ushort* __restrict__ Yr) {
    constexpr int KS = K / 32;
    const int lane  = threadIdx.x & 63;
    const int wave  = threadIdx.x >> 6;
    const int nhalf = wave & 1;
    const int rsub  = wave >> 1;
    const int m = lane & 15, quad = lane >> 4;

    v8bf bl[KS][2], br[KS][2];
#pragma unroll
    for (int ks = 0; ks < KS; ++ks)
#pragma unroll
        for (int nt = 0; nt < 2; ++nt) {
            const int nti = nhalf * 2 + nt;
            bl[ks][nt] = *(const v8bf*)(Bl + ((size_t)(ks * 4 + nti) * 64 + lane) * 8);
            br[ks][nt] = *(const v8bf*)(Br + ((size_t)(ks * 4 + nti) * 64 + lane) * 8);
        }

    for (int it = 0; it < TPB; ++it) {
        const int bt = blockIdx.x * TPB + it;
        const int row0 = bt * 32 + rsub * 16;
        if (row0 >= NN) return;
        const v4f z = {0.f, 0.f, 0.f, 0.f};
        v4f accl[2] = {z, z}, accr[2] = {z, z};
#pragma unroll
        for (int ks = 0; ks < KS; ++ks) {
            v8bf a;
            if (AF32) {
                const float* xrow = (const float*)Xv + (size_t)(row0 + m) * K + quad * 8 + ks * 32;
                const float4 a0 = *(const float4*)(xrow);
                const float4 a1 = *(const float4*)(xrow + 4);
                a[0] = (short)f2b(a0.x); a[1] = (short)f2b(a0.y);
                a[2] = (short)f2b(a0.z); a[3] = (short)f2b(a0.w);
                a[4] = (short)f2b(a1.x); a[5] = (short)f2b(a1.y);
                a[6] = (short)f2b(a1.z); a[7] = (short)f2b(a1.w);
            } else {
                const ushort* xrow = (const ushort*)Xv + (size_t)(row0 + m) * K + quad * 8 + ks * 32;
                a = *(const v8bf*)xrow;
            }
#pragma unroll
            for (int nt = 0; nt < 2; ++nt) {
                accl[nt] = __builtin_amdgcn_mfma_f32_16x16x32_bf16(a, bl[ks][nt], accl[nt], 0, 0, 0);
                accr[nt] = __builtin_amdgcn_mfma_f32_16x16x32_bf16(a, br[ks][nt], accr[nt], 0, 0, 0);
            }
        }
#pragma unroll
        for (int nt = 0; nt < 2; ++nt) {
            const int cc = nhalf * 32 + nt * 16 + m;
#pragma unroll
            for (int r = 0; r < 4; ++r) {
                const size_t off = (size_t)(row0 + quad * 4 + r) * 64 + cc;
                Yl[off] = f2b(accl[nt][r]);
                Yr[off] = f2b(accr[nt][r]);
            }
        }
    }
}

// ---------------- pass A: bucket edges, packed (src<<7)|dstLocal ----------------
// sub-segment keyed by blockIdx&7: with round-robin block->XCD dispatch each
// sub-segment's append stream stays XCD-local so L2 lines fill before eviction.
__global__ __launch_bounds__(256) void bucket_scatter(const int* __restrict__ src,
                                                      const int* __restrict__ dst,
                                                      int* __restrict__ bcnt,
                                                      int* __restrict__ pairs) {
    const int g = blockIdx.x & (NSUB - 1);
    for (int e = blockIdx.x * 256 + threadIdx.x; e < NE; e += SCAT_BLOCKS * 256) {
        const int s = src[e];
        const int d = dst[e];
        const int b = d >> 7;
        const int pos = atomicAdd(&bcnt[b * NSUB + g], 1);
        if (pos < BCAP)
            pairs[((size_t)(b * NSUB + g)) * BCAP + pos] = (s << 7) | (d & (BNODES - 1));
    }
}

// ---------------- pass B: fused SpMM(mean) + bias + root + BN + ReLU ----------------
// one block per bucket; fp32 accumulator in LDS (padded stride 65).
template<bool BF16OUT>
__global__ __launch_bounds__(256) void spmm_fused(const int* __restrict__ bcnt,
                                                  const int* __restrict__ pairs,
                                                  const ushort* __restrict__ Yl,
                                                  const ushort* __restrict__ Yr,
                                                  const float* __restrict__ bias,
                                                  const float* __restrict__ bng,
                                                  const float* __restrict__ bnb,
                                                  const float* __restrict__ bnm,
                                                  const float* __restrict__ bnv,
                                                  void* __restrict__ outp) {
    __shared__ float acc[BNODES * 65];
    __shared__ int scnt[BNODES];
    const int tid = threadIdx.x;
    const int b = blockIdx.x;
    for (int i = tid; i < BNODES * 65; i += 256) acc[i] = 0.f;
    if (tid < BNODES) scnt[tid] = 0;
    __syncthreads();

    const int wv = tid >> 6, lane = tid & 63;
    const int grp = lane >> 3, sub = lane & 7;   // 8 edges/wave-iter, 8 lanes/edge

    for (int g = 0; g < NSUB; ++g) {
        const int len = bcnt[b * NSUB + g];
        const int* seg = pairs + (size_t)(b * NSUB + g) * BCAP;
        for (int base = wv * 8; base < len; base += 32) {
            const int ei = base + grp;
            if (ei < len) {
                const int pv = seg[ei];
                const int s = pv >> 7, dl = pv & (BNODES - 1);
                const uint4 r = *(const uint4*)(Yl + (size_t)s * 64 + sub * 8);
                float* arow = &acc[dl * 65 + sub * 8];
                const unsigned u0 = r.x, u1 = r.y, u2 = r.z, u3 = r.w;
                atomicAdd(arow + 0, __uint_as_float(u0 << 16));
                atomicAdd(arow + 1, __uint_as_float(u0 & 0xffff0000u));
                atomicAdd(arow + 2, __uint_as_float(u1 << 16));
                atomicAdd(arow + 3, __uint_as_float(u1 & 0xffff0000u));
                atomicAdd(arow + 4, __uint_as_float(u2 << 16));
                atomicAdd(arow + 5, __uint_as_float(u2 & 0xffff0000u));
                atomicAdd(arow + 6, __uint_as_float(u3 << 16));
                atomicAdd(arow + 7, __uint_as_float(u3 & 0xffff0000u));
                if (sub == 0) atomicAdd(&scnt[dl], 1);
            }
        }
    }
    __syncthreads();

    // epilogue: wave wv -> nodes [wv*32, wv*32+32), lane = channel
    const float biasl = bias[lane];
    const float scale = bng[lane] * rsqrtf(bnv[lane] + BN_EPS);
    const float bnbv = bnb[lane], bnmv = bnm[lane];
    for (int i = 0; i < 32; ++i) {
        const int nl = wv * 32 + i;
        const int node = b * BNODES + nl;
        if (node >= NN) break;
        const float cv = (float)scnt[nl];
        const float mean = acc[nl * 65 + lane] / fmaxf(cv, 1.0f);
        const float h = mean + biasl + b2f(Yr[(size_t)node * 64 + lane]);
        const float val = fmaxf((h - bnmv) * scale + bnbv, 0.0f);
        const size_t idx = (size_t)node * 64 + lane;
        if (BF16OUT) ((ushort*)outp)[idx] = f2b(val);
        else         ((float*)outp)[idx] = val;
    }
}

// ---------------- segmented global mean pool (batch sorted, h in bf16) ----------------
__global__ __launch_bounds__(256) void pool_seg(const ushort* __restrict__ h,
                                                const int* __restrict__ batch,
                                                float* __restrict__ gsum,
                                                float* __restrict__ gcnt) {
    const int wave = blockIdx.x * 4 + (threadIdx.x >> 6);
    const int lane = threadIdx.x & 63;
    const int n0 = wave * 256;
    if (n0 >= NN) return;
    const int n1 = (n0 + 256 < NN) ? n0 + 256 : NN;
    int g = batch[n0];
    float acc = 0.f, c = 0.f;
    for (int n = n0; n < n1; ++n) {
        const int b = batch[n];
        if (b != g) {
            atomicAdd(&gsum[g * 64 + lane], acc);
            if (lane == 0) atomicAdd(&gcnt[g], c);
            acc = 0.f; c = 0.f; g = b;
        }
        acc += b2f(h[(size_t)n * 64 + lane]);
        c += 1.0f;
    }
    atomicAdd(&gsum[g * 64 + lane], acc);
    if (lane == 0) atomicAdd(&gcnt[g], c);
}

// ---------------- classifier head ----------------
__global__ __launch_bounds__(64) void head_kernel(const float* __restrict__ gsum,
                                                  const float* __restrict__ gcnt,
                                                  const float* __restrict__ Wc1,
                                                  const float* __restrict__ bc1,
                                                  const float* __restrict__ g3,
                                                  const float* __restrict__ b3,
                                                  const float* __restrict__ m3,
                                                  const float* __restrict__ v3,
                                                  const float* __restrict__ Wc2,
                                                  const float* __restrict__ bc2,
                                                  float* __restrict__ out) {
    __shared__ float sg[64];
    __shared__ float st[64];
    __shared__ float sl[10];
    __shared__ float sls;
    const int b = blockIdx.x;
    const int c = threadIdx.x;
    sg[c] = gsum[b * 64 + c] / fmaxf(gcnt[b], 1.0f);
    __syncthreads();
    float acc = bc1[c];
#pragma unroll
    for (int k = 0; k < 64; ++k) acc += sg[k] * Wc1[k * 64 + c];
    const float sc = g3[c] * rsqrtf(v3[c] + BN_EPS);
    st[c] = fmaxf((acc - m3[c]) * sc + b3[c], 0.0f);
    __syncthreads();
    if (c < CC) {
        float lg = bc2[c];
#pragma unroll
        for (int k = 0; k < 64; ++k) lg += st[k] * Wc2[k * CC + c];
        sl[c] = lg;
    }
    __syncthreads();
    if (c == 0) {
        float mx = sl[0];
        for (int i = 1; i < CC; ++i) mx = fmaxf(mx, sl[i]);
        float s = 0.f;
        for (int i = 0; i < CC; ++i) s += expf(sl[i] - mx);
        sls = mx + logf(s);
    }
    __syncthreads();
    if (c < CC) out[b * CC + c] = sl[c] - sls;
}

extern "C" void kernel_launch(void* const* d_in, const int* in_sizes, int n_in,
                              void* d_out, int out_size, void* d_ws, size_t ws_size,
                              hipStream_t stream) {
    const float* x    = (const float*)d_in[0];
    const int*   ei   = (const int*)d_in[1];
    const int*   batch= (const int*)d_in[2];
    const float* W1l  = (const float*)d_in[3];
    const float* W1r  = (const float*)d_in[4];
    const float* b1   = (const float*)d_in[5];
    const float* W2l  = (const float*)d_in[6];
    const float* W2r  = (const float*)d_in[7];
    const float* b2   = (const float*)d_in[8];
    const float* bn1g = (const float*)d_in[9];
    const float* bn1b = (const float*)d_in[10];
    const float* bn1m = (const float*)d_in[11];
    const float* bn1v = (const float*)d_in[12];
    const float* bn2g = (const float*)d_in[13];
    const float* bn2b = (const float*)d_in[14];
    const float* bn2m = (const float*)d_in[15];
    const float* bn2v = (const float*)d_in[16];
    const float* bn3g = (const float*)d_in[17];
    const float* bn3b = (const float*)d_in[18];
    const float* bn3m = (const float*)d_in[19];
    const float* bn3v = (const float*)d_in[20];
    const float* Wc1  = (const float*)d_in[21];
    const float* bc1  = (const float*)d_in[22];
    const float* Wc2  = (const float*)d_in[23];
    const float* bc2  = (const float*)d_in[24];
    float* out = (float*)d_out;

    const int* src = ei;
    const int* dst = ei + NE;

    // workspace layout (all blocks 16B-aligned)
    char* p = (char*)d_ws;
    ushort* yl   = (ushort*)p;                 p += (size_t)NN * 64 * 2;           // 12.8 MB
    ushort* yr   = (ushort*)p;                 p += (size_t)NN * 64 * 2;           // 12.8 MB
    ushort* hbuf = (ushort*)p;                 p += (size_t)NN * 64 * 2;           // 12.8 MB
    int*    pairs= (int*)p;                    p += (size_t)NB * NSUB * BCAP * 4;  // 12.8 MB
    int*    bcnt = (int*)p;                    p += (size_t)NB * NSUB * 4;         // 25 KB
    ushort* w1ls = (ushort*)p;                 p += (size_t)FF * 64 * 2;
    ushort* w1rs = (ushort*)p;                 p += (size_t)FF * 64 * 2;
    ushort* w2ls = (ushort*)p;                 p += (size_t)HH * 64 * 2;
    ushort* w2rs = (ushort*)p;                 p += (size_t)HH * 64 * 2;
    float* gsum  = (float*)p;                  p += (size_t)GG * 64 * 4;
    float* gcnt  = (float*)p;                  p += (size_t)GG * 4;

    // ---- edge bucketing (once, reused by both layers) ----
    hipMemsetAsync(bcnt, 0, (size_t)NB * NSUB * sizeof(int), stream);
    bucket_scatter<<<SCAT_BLOCKS, 256, 0, stream>>>(src, dst, bcnt, pairs);

    // ---- weight swizzles ----
    w_swizzle<FF><<<((FF / 32) * 256 + 255) / 256, 256, 0, stream>>>(W1l, W1r, w1ls, w1rs);
    w_swizzle<HH><<<((HH / 32) * 256 + 255) / 256, 256, 0, stream>>>(W2l, W2r, w2ls, w2rs);

    // ---- layer 1 ----
    gemm_mfma<FF, 5, true><<<625, 256, 0, stream>>>((const void*)x, w1ls, w1rs, yl, yr);
    spmm_fused<true><<<NB, 256, 0, stream>>>(bcnt, pairs, yl, yr, b1,
                                             bn1g, bn1b, bn1m, bn1v, (void*)hbuf);

    // ---- layer 2 ----
    gemm_mfma<HH, 5, false><<<625, 256, 0, stream>>>((const void*)hbuf, w2ls, w2rs, yl, yr);
    spmm_fused<true><<<NB, 256, 0, stream>>>(bcnt, pairs, yl, yr, b2,
                                             bn2g, bn2b, bn2m, bn2v, (void*)hbuf);

    // ---- pool + head ----
    hipMemsetAsync(gsum, 0, (size_t)(GG * 64 + GG) * sizeof(float), stream);
    pool_seg<<<98, 256, 0, stream>>>(hbuf, batch, gsum, gcnt);
    head_kernel<<<GG, 64, 0, stream>>>(gsum, gcnt, Wc1, bc1,
                                       bn3g, bn3b, bn3m, bn3v, Wc2, bc2, out);
}

// Round 6
// 457.605 us; speedup vs baseline: 3.7446x; 3.7446x over previous
//
#include <hip/hip_runtime.h>
#include <hip/hip_bf16.h>
#include <math.h>

#define NN 100000
#define NE 1600000
#define FF 128
#define HH 64
#define CC 10
#define GG 128
#define BN_EPS 1e-5f

// bucketed-edge constants
#define BNODES 128              // nodes per bucket (dst>>7)
#define NB 782                  // ceil(NN/BNODES)
#define NSUB 8                  // append sub-streams per bucket
#define BCAP 512                // capacity per (bucket,sub): mean 256, +16 sigma
#define SCAT_BLOCKS 2048        // pass-A grid

typedef short v8bf __attribute__((ext_vector_type(8)));
typedef float v4f  __attribute__((ext_vector_type(4)));

__device__ inline ushort f2b(float x) {
    __hip_bfloat16 h = __float2bfloat16(x);
    return *reinterpret_cast<ushort*>(&h);
}
__device__ inline float b2f(ushort u) {
    return __uint_as_float(((unsigned)u) << 16);
}
__device__ inline float blo(unsigned u) { return __uint_as_float(u << 16); }
__device__ inline float bhi(unsigned u) { return __uint_as_float(u & 0xffff0000u); }

// ---------------- W [K][64] fp32 -> bf16 swizzled into MFMA B-fragment order ----------
template<int K>
__global__ __launch_bounds__(256) void w_swizzle(const float* __restrict__ Wl,
                                                 const float* __restrict__ Wr,
                                                 ushort* __restrict__ ol,
                                                 ushort* __restrict__ orr) {
    constexpr int T = (K / 32) * 4 * 64;
    const int t = blockIdx.x * 256 + threadIdx.x;
    if (t >= T) return;
    const int lane = t & 63, nt = (t >> 6) & 3, ks = t >> 8;
    const int m = lane & 15, quad = lane >> 4;
#pragma unroll
    for (int j = 0; j < 8; ++j) {
        const int kk = ks * 32 + quad * 8 + j;
        const int cc = nt * 16 + m;
        ol[t * 8 + j]  = f2b(Wl[kk * 64 + cc]);
        orr[t * 8 + j] = f2b(Wr[kk * 64 + cc]);
    }
}

// ---------------- dual MFMA GEMM: Yl = X@Wl, Yr = X@Wr (bf16 out) ----------------
template<int K, int TPB, bool AF32>
__global__ __launch_bounds__(256) void gemm_mfma(const void* __restrict__ Xv,
                                                 const ushort* __restrict__ Bl,
                                                 const ushort* __restrict__ Br,
                                                 ushort* __restrict__ Yl,
                                                 ushort* __restrict__ Yr) {
    constexpr int KS = K / 32;
    const int lane  = threadIdx.x & 63;
    const int wave  = threadIdx.x >> 6;
    const int nhalf = wave & 1;
    const int rsub  = wave >> 1;
    const int m = lane & 15, quad = lane >> 4;

    v8bf bl[KS][2], br[KS][2];
#pragma unroll
    for (int ks = 0; ks < KS; ++ks)
#pragma unroll
        for (int nt = 0; nt < 2; ++nt) {
            const int nti = nhalf * 2 + nt;
            bl[ks][nt] = *(const v8bf*)(Bl + ((size_t)(ks * 4 + nti) * 64 + lane) * 8);
            br[ks][nt] = *(const v8bf*)(Br + ((size_t)(ks * 4 + nti) * 64 + lane) * 8);
        }

    for (int it = 0; it < TPB; ++it) {
        const int bt = blockIdx.x * TPB + it;
        const int row0 = bt * 32 + rsub * 16;
        if (row0 >= NN) return;
        const v4f z = {0.f, 0.f, 0.f, 0.f};
        v4f accl[2] = {z, z}, accr[2] = {z, z};
#pragma unroll
        for (int ks = 0; ks < KS; ++ks) {
            v8bf a;
            if (AF32) {
                const float* xrow = (const float*)Xv + (size_t)(row0 + m) * K + quad * 8 + ks * 32;
                const float4 a0 = *(const float4*)(xrow);
                const float4 a1 = *(const float4*)(xrow + 4);
                a[0] = (short)f2b(a0.x); a[1] = (short)f2b(a0.y);
                a[2] = (short)f2b(a0.z); a[3] = (short)f2b(a0.w);
                a[4] = (short)f2b(a1.x); a[5] = (short)f2b(a1.y);
                a[6] = (short)f2b(a1.z); a[7] = (short)f2b(a1.w);
            } else {
                const ushort* xrow = (const ushort*)Xv + (size_t)(row0 + m) * K + quad * 8 + ks * 32;
                a = *(const v8bf*)xrow;
            }
#pragma unroll
            for (int nt = 0; nt < 2; ++nt) {
                accl[nt] = __builtin_amdgcn_mfma_f32_16x16x32_bf16(a, bl[ks][nt], accl[nt], 0, 0, 0);
                accr[nt] = __builtin_amdgcn_mfma_f32_16x16x32_bf16(a, br[ks][nt], accr[nt], 0, 0, 0);
            }
        }
#pragma unroll
        for (int nt = 0; nt < 2; ++nt) {
            const int cc = nhalf * 32 + nt * 16 + m;
#pragma unroll
            for (int r = 0; r < 4; ++r) {
                const size_t off = (size_t)(row0 + quad * 4 + r) * 64 + cc;
                Yl[off] = f2b(accl[nt][r]);
                Yr[off] = f2b(accr[nt][r]);
            }
        }
    }
}

// ---------------- pass A: bucket edges, packed (src<<7)|dstLocal ----------------
// append streams: atomic position allocation makes temporally-close appends land in
// the same cacheline -> dense writebacks (validated round 5: not in top-5).
__global__ __launch_bounds__(256) void bucket_scatter(const int* __restrict__ src,
                                                      const int* __restrict__ dst,
                                                      int* __restrict__ bcnt,
                                                      int* __restrict__ pairs) {
    const int g = blockIdx.x & (NSUB - 1);
    for (int e = blockIdx.x * 256 + threadIdx.x; e < NE; e += SCAT_BLOCKS * 256) {
        const int s = src[e];
        const int d = dst[e];
        const int b = d >> 7;
        const int pos = atomicAdd(&bcnt[b * NSUB + g], 1);
        if (pos < BCAP)
            pairs[((size_t)(b * NSUB + g)) * BCAP + pos] = (s << 7) | (d & (BNODES - 1));
    }
}

// ---------------- pass B: LDS counting-sort + register-gather + fused epilogue -------
// one block per bucket. No accumulator atomics: sort edges by dstLocal in LDS,
// then 16 lanes/node (4 channels/lane) register-accumulate.
__global__ __launch_bounds__(256) void spmm_sorted(const int* __restrict__ bcnt,
                                                   const int* __restrict__ pairs,
                                                   const ushort* __restrict__ Yl,
                                                   const ushort* __restrict__ Yr,
                                                   const float* __restrict__ bias,
                                                   const float* __restrict__ bng,
                                                   const float* __restrict__ bnb,
                                                   const float* __restrict__ bnm,
                                                   const float* __restrict__ bnv,
                                                   ushort* __restrict__ outp) {
    __shared__ int scol[NSUB * BCAP];   // 16 KB: sorted src ids
    __shared__ int deg[BNODES];
    __shared__ int offs[BNODES];        // inclusive scan of deg
    __shared__ int fill[BNODES];
    __shared__ int slen[NSUB];
    const int tid = threadIdx.x;
    const int b = blockIdx.x;

    if (tid < BNODES) { deg[tid] = 0; fill[tid] = 0; }
    if (tid < NSUB) {
        int l = bcnt[b * NSUB + tid];
        slen[tid] = l > BCAP ? BCAP : l;
    }
    __syncthreads();

    // phase 1: per-dstLocal degree count (LDS counter atomics only)
    for (int g = 0; g < NSUB; ++g) {
        const int len = slen[g];
        const int* seg = pairs + (size_t)(b * NSUB + g) * BCAP;
        for (int i = tid; i < len; i += 256)
            atomicAdd(&deg[seg[i] & (BNODES - 1)], 1);
    }
    __syncthreads();

    // phase 2: inclusive scan of deg -> offs (Hillis-Steele over 128)
    if (tid < BNODES) offs[tid] = deg[tid];
    __syncthreads();
    for (int s = 1; s < BNODES; s <<= 1) {
        int v = 0;
        if (tid < BNODES && tid >= s) v = offs[tid - s];
        __syncthreads();
        if (tid < BNODES) offs[tid] += v;
        __syncthreads();
    }

    // phase 3: scatter src ids into sorted order
    for (int g = 0; g < NSUB; ++g) {
        const int len = slen[g];
        const int* seg = pairs + (size_t)(b * NSUB + g) * BCAP;
        for (int i = tid; i < len; i += 256) {
            const int pv = seg[i];
            const int dl = pv & (BNODES - 1);
            const int pos = (offs[dl] - deg[dl]) + atomicAdd(&fill[dl], 1);
            scol[pos] = pv >> 7;
        }
    }
    __syncthreads();

    // phase 4: gather + mean + bias + root + BN + ReLU
    // wave wv handles nodes [wv*32, wv*32+32); 4 concurrent node-groups of 16 lanes.
    const int wv = tid >> 6, lane = tid & 63;
    const int grp = lane >> 4, subl = lane & 15;

    const float4 bias4 = *(const float4*)(bias + subl * 4);
    const float4 g4 = *(const float4*)(bng + subl * 4);
    const float4 v4 = *(const float4*)(bnv + subl * 4);
    const float4 m4 = *(const float4*)(bnm + subl * 4);
    const float4 bb4 = *(const float4*)(bnb + subl * 4);
    const float sc0 = g4.x * rsqrtf(v4.x + BN_EPS);
    const float sc1 = g4.y * rsqrtf(v4.y + BN_EPS);
    const float sc2 = g4.z * rsqrtf(v4.z + BN_EPS);
    const float sc3 = g4.w * rsqrtf(v4.w + BN_EPS);

    for (int i = 0; i < 8; ++i) {
        const int nl = wv * 32 + i * 4 + grp;
        const int node = b * BNODES + nl;
        if (node >= NN) continue;
        const int dg = deg[nl];
        const int beg = offs[nl] - dg;
        const int end = beg + dg;
        float a0 = 0.f, a1 = 0.f, a2 = 0.f, a3 = 0.f;
        float c0 = 0.f, c1 = 0.f, c2 = 0.f, c3 = 0.f;
        int e = beg;
        for (; e + 1 < end; e += 2) {
            const int s0 = scol[e];
            const int s1 = scol[e + 1];
            const uint2 r0 = *(const uint2*)(Yl + (size_t)s0 * 64 + subl * 4);
            const uint2 r1 = *(const uint2*)(Yl + (size_t)s1 * 64 + subl * 4);
            a0 += blo(r0.x); a1 += bhi(r0.x); a2 += blo(r0.y); a3 += bhi(r0.y);
            c0 += blo(r1.x); c1 += bhi(r1.x); c2 += blo(r1.y); c3 += bhi(r1.y);
        }
        if (e < end) {
            const int s0 = scol[e];
            const uint2 r0 = *(const uint2*)(Yl + (size_t)s0 * 64 + subl * 4);
            a0 += blo(r0.x); a1 += bhi(r0.x); a2 += blo(r0.y); a3 += bhi(r0.y);
        }
        a0 += c0; a1 += c1; a2 += c2; a3 += c3;
        const float inv = 1.0f / fmaxf((float)dg, 1.0f);
        const uint2 yr = *(const uint2*)(Yr + (size_t)node * 64 + subl * 4);
        const float h0 = a0 * inv + bias4.x + blo(yr.x);
        const float h1 = a1 * inv + bias4.y + bhi(yr.x);
        const float h2 = a2 * inv + bias4.z + blo(yr.y);
        const float h3 = a3 * inv + bias4.w + bhi(yr.y);
        const float o0 = fmaxf((h0 - m4.x) * sc0 + bb4.x, 0.0f);
        const float o1 = fmaxf((h1 - m4.y) * sc1 + bb4.y, 0.0f);
        const float o2 = fmaxf((h2 - m4.z) * sc2 + bb4.z, 0.0f);
        const float o3 = fmaxf((h3 - m4.w) * sc3 + bb4.w, 0.0f);
        uint2 o;
        o.x = (unsigned)f2b(o0) | ((unsigned)f2b(o1) << 16);
        o.y = (unsigned)f2b(o2) | ((unsigned)f2b(o3) << 16);
        *(uint2*)(outp + (size_t)node * 64 + subl * 4) = o;
    }
}

// ---------------- segmented global mean pool (batch sorted, h in bf16) ----------------
__global__ __launch_bounds__(256) void pool_seg(const ushort* __restrict__ h,
                                                const int* __restrict__ batch,
                                                float* __restrict__ gsum,
                                                float* __restrict__ gcnt) {
    const int wave = blockIdx.x * 4 + (threadIdx.x >> 6);
    const int lane = threadIdx.x & 63;
    const int n0 = wave * 256;
    if (n0 >= NN) return;
    const int n1 = (n0 + 256 < NN) ? n0 + 256 : NN;
    int g = batch[n0];
    float acc = 0.f, c = 0.f;
    for (int n = n0; n < n1; ++n) {
        const int b = batch[n];
        if (b != g) {
            atomicAdd(&gsum[g * 64 + lane], acc);
            if (lane == 0) atomicAdd(&gcnt[g], c);
            acc = 0.f; c = 0.f; g = b;
        }
        acc += b2f(h[(size_t)n * 64 + lane]);
        c += 1.0f;
    }
    atomicAdd(&gsum[g * 64 + lane], acc);
    if (lane == 0) atomicAdd(&gcnt[g], c);
}

// ---------------- classifier head ----------------
__global__ __launch_bounds__(64) void head_kernel(const float* __restrict__ gsum,
                                                  const float* __restrict__ gcnt,
                                                  const float* __restrict__ Wc1,
                                                  const float* __restrict__ bc1,
                                                  const float* __restrict__ g3,
                                                  const float* __restrict__ b3,
                                                  const float* __restrict__ m3,
                                                  const float* __restrict__ v3,
                                                  const float* __restrict__ Wc2,
                                                  const float* __restrict__ bc2,
                                                  float* __restrict__ out) {
    __shared__ float sg[64];
    __shared__ float st[64];
    __shared__ float sl[10];
    __shared__ float sls;
    const int b = blockIdx.x;
    const int c = threadIdx.x;
    sg[c] = gsum[b * 64 + c] / fmaxf(gcnt[b], 1.0f);
    __syncthreads();
    float acc = bc1[c];
#pragma unroll
    for (int k = 0; k < 64; ++k) acc += sg[k] * Wc1[k * 64 + c];
    const float sc = g3[c] * rsqrtf(v3[c] + BN_EPS);
    st[c] = fmaxf((acc - m3[c]) * sc + b3[c], 0.0f);
    __syncthreads();
    if (c < CC) {
        float lg = bc2[c];
#pragma unroll
        for (int k = 0; k < 64; ++k) lg += st[k] * Wc2[k * CC + c];
        sl[c] = lg;
    }
    __syncthreads();
    if (c == 0) {
        float mx = sl[0];
        for (int i = 1; i < CC; ++i) mx = fmaxf(mx, sl[i]);
        float s = 0.f;
        for (int i = 0; i < CC; ++i) s += expf(sl[i] - mx);
        sls = mx + logf(s);
    }
    __syncthreads();
    if (c < CC) out[b * CC + c] = sl[c] - sls;
}

extern "C" void kernel_launch(void* const* d_in, const int* in_sizes, int n_in,
                              void* d_out, int out_size, void* d_ws, size_t ws_size,
                              hipStream_t stream) {
    const float* x    = (const float*)d_in[0];
    const int*   ei   = (const int*)d_in[1];
    const int*   batch= (const int*)d_in[2];
    const float* W1l  = (const float*)d_in[3];
    const float* W1r  = (const float*)d_in[4];
    const float* b1   = (const float*)d_in[5];
    const float* W2l  = (const float*)d_in[6];
    const float* W2r  = (const float*)d_in[7];
    const float* b2   = (const float*)d_in[8];
    const float* bn1g = (const float*)d_in[9];
    const float* bn1b = (const float*)d_in[10];
    const float* bn1m = (const float*)d_in[11];
    const float* bn1v = (const float*)d_in[12];
    const float* bn2g = (const float*)d_in[13];
    const float* bn2b = (const float*)d_in[14];
    const float* bn2m = (const float*)d_in[15];
    const float* bn2v = (const float*)d_in[16];
    const float* bn3g = (const float*)d_in[17];
    const float* bn3b = (const float*)d_in[18];
    const float* bn3m = (const float*)d_in[19];
    const float* bn3v = (const float*)d_in[20];
    const float* Wc1  = (const float*)d_in[21];
    const float* bc1  = (const float*)d_in[22];
    const float* Wc2  = (const float*)d_in[23];
    const float* bc2  = (const float*)d_in[24];
    float* out = (float*)d_out;

    const int* src = ei;
    const int* dst = ei + NE;

    // workspace layout (all blocks 16B-aligned)
    char* p = (char*)d_ws;
    ushort* yl   = (ushort*)p;                 p += (size_t)NN * 64 * 2;           // 12.8 MB
    ushort* yr   = (ushort*)p;                 p += (size_t)NN * 64 * 2;           // 12.8 MB
    ushort* hbuf = (ushort*)p;                 p += (size_t)NN * 64 * 2;           // 12.8 MB
    int*    pairs= (int*)p;                    p += (size_t)NB * NSUB * BCAP * 4;  // 12.8 MB
    int*    bcnt = (int*)p;                    p += (size_t)NB * NSUB * 4;         // 25 KB
    ushort* w1ls = (ushort*)p;                 p += (size_t)FF * 64 * 2;
    ushort* w1rs = (ushort*)p;                 p += (size_t)FF * 64 * 2;
    ushort* w2ls = (ushort*)p;                 p += (size_t)HH * 64 * 2;
    ushort* w2rs = (ushort*)p;                 p += (size_t)HH * 64 * 2;
    float* gsum  = (float*)p;                  p += (size_t)GG * 64 * 4;
    float* gcnt  = (float*)p;                  p += (size_t)GG * 4;

    // ---- edge bucketing (once, reused by both layers) ----
    hipMemsetAsync(bcnt, 0, (size_t)NB * NSUB * sizeof(int), stream);
    bucket_scatter<<<SCAT_BLOCKS, 256, 0, stream>>>(src, dst, bcnt, pairs);

    // ---- weight swizzles ----
    w_swizzle<FF><<<((FF / 32) * 256 + 255) / 256, 256, 0, stream>>>(W1l, W1r, w1ls, w1rs);
    w_swizzle<HH><<<((HH / 32) * 256 + 255) / 256, 256, 0, stream>>>(W2l, W2r, w2ls, w2rs);

    // ---- layer 1 ----
    gemm_mfma<FF, 5, true><<<625, 256, 0, stream>>>((const void*)x, w1ls, w1rs, yl, yr);
    spmm_sorted<<<NB, 256, 0, stream>>>(bcnt, pairs, yl, yr, b1,
                                        bn1g, bn1b, bn1m, bn1v, hbuf);

    // ---- layer 2 ----
    gemm_mfma<HH, 5, false><<<625, 256, 0, stream>>>((const void*)hbuf, w2ls, w2rs, yl, yr);
    spmm_sorted<<<NB, 256, 0, stream>>>(bcnt, pairs, yl, yr, b2,
                                        bn2g, bn2b, bn2m, bn2v, hbuf);

    // ---- pool + head ----
    hipMemsetAsync(gsum, 0, (size_t)(GG * 64 + GG) * sizeof(float), stream);
    pool_seg<<<98, 256, 0, stream>>>(hbuf, batch, gsum, gcnt);
    head_kernel<<<GG, 64, 0, stream>>>(gsum, gcnt, Wc1, bc1,
                                       bn3g, bn3b, bn3m, bn3v, Wc2, bc2, out);
}

// Round 7
// 392.464 us; speedup vs baseline: 4.3661x; 1.1660x over previous
//
#include <hip/hip_runtime.h>
#include <hip/hip_bf16.h>
#include <math.h>

#define NN 100000
#define NE 1600000
#define FF 128
#define HH 64
#define CC 10
#define GG 128
#define BN_EPS 1e-5f

// bucketed-edge constants
#define BNODES 128              // nodes per bucket (dst>>7)
#define NB 782                  // ceil(NN/BNODES)
#define NSUB 8                  // append sub-streams per bucket
#define BCAP 512                // capacity per (bucket,sub): mean 256, +16 sigma
#define SCAT_BLOCKS 2048        // pass-A grid

// pool constants
#define PNODES 16               // nodes per wave in pool (6250 waves total)
#define POOL_BLOCKS 1563        // ceil(100000/16/4)

typedef short v8bf __attribute__((ext_vector_type(8)));
typedef float v4f  __attribute__((ext_vector_type(4)));

__device__ inline ushort f2b(float x) {
    __hip_bfloat16 h = __float2bfloat16(x);
    return *reinterpret_cast<ushort*>(&h);
}
__device__ inline float b2f(ushort u) {
    return __uint_as_float(((unsigned)u) << 16);
}
__device__ inline float blo(unsigned u) { return __uint_as_float(u << 16); }
__device__ inline float bhi(unsigned u) { return __uint_as_float(u & 0xffff0000u); }

// ---------------- W [K][64] fp32 -> bf16 swizzled into MFMA B-fragment order ----------
template<int K>
__global__ __launch_bounds__(256) void w_swizzle(const float* __restrict__ Wl,
                                                 const float* __restrict__ Wr,
                                                 ushort* __restrict__ ol,
                                                 ushort* __restrict__ orr) {
    constexpr int T = (K / 32) * 4 * 64;
    const int t = blockIdx.x * 256 + threadIdx.x;
    if (t >= T) return;
    const int lane = t & 63, nt = (t >> 6) & 3, ks = t >> 8;
    const int m = lane & 15, quad = lane >> 4;
#pragma unroll
    for (int j = 0; j < 8; ++j) {
        const int kk = ks * 32 + quad * 8 + j;
        const int cc = nt * 16 + m;
        ol[t * 8 + j]  = f2b(Wl[kk * 64 + cc]);
        orr[t * 8 + j] = f2b(Wr[kk * 64 + cc]);
    }
}

// ---------------- dual MFMA GEMM: Yl = X@Wl, Yr = X@Wr (bf16 out) ----------------
template<int K, int TPB, bool AF32>
__global__ __launch_bounds__(256) void gemm_mfma(const void* __restrict__ Xv,
                                                 const ushort* __restrict__ Bl,
                                                 const ushort* __restrict__ Br,
                                                 ushort* __restrict__ Yl,
                                                 ushort* __restrict__ Yr) {
    constexpr int KS = K / 32;
    const int lane  = threadIdx.x & 63;
    const int wave  = threadIdx.x >> 6;
    const int nhalf = wave & 1;
    const int rsub  = wave >> 1;
    const int m = lane & 15, quad = lane >> 4;

    v8bf bl[KS][2], br[KS][2];
#pragma unroll
    for (int ks = 0; ks < KS; ++ks)
#pragma unroll
        for (int nt = 0; nt < 2; ++nt) {
            const int nti = nhalf * 2 + nt;
            bl[ks][nt] = *(const v8bf*)(Bl + ((size_t)(ks * 4 + nti) * 64 + lane) * 8);
            br[ks][nt] = *(const v8bf*)(Br + ((size_t)(ks * 4 + nti) * 64 + lane) * 8);
        }

    for (int it = 0; it < TPB; ++it) {
        const int bt = blockIdx.x * TPB + it;
        const int row0 = bt * 32 + rsub * 16;
        if (row0 >= NN) return;
        const v4f z = {0.f, 0.f, 0.f, 0.f};
        v4f accl[2] = {z, z}, accr[2] = {z, z};
#pragma unroll
        for (int ks = 0; ks < KS; ++ks) {
            v8bf a;
            if (AF32) {
                const float* xrow = (const float*)Xv + (size_t)(row0 + m) * K + quad * 8 + ks * 32;
                const float4 a0 = *(const float4*)(xrow);
                const float4 a1 = *(const float4*)(xrow + 4);
                a[0] = (short)f2b(a0.x); a[1] = (short)f2b(a0.y);
                a[2] = (short)f2b(a0.z); a[3] = (short)f2b(a0.w);
                a[4] = (short)f2b(a1.x); a[5] = (short)f2b(a1.y);
                a[6] = (short)f2b(a1.z); a[7] = (short)f2b(a1.w);
            } else {
                const ushort* xrow = (const ushort*)Xv + (size_t)(row0 + m) * K + quad * 8 + ks * 32;
                a = *(const v8bf*)xrow;
            }
#pragma unroll
            for (int nt = 0; nt < 2; ++nt) {
                accl[nt] = __builtin_amdgcn_mfma_f32_16x16x32_bf16(a, bl[ks][nt], accl[nt], 0, 0, 0);
                accr[nt] = __builtin_amdgcn_mfma_f32_16x16x32_bf16(a, br[ks][nt], accr[nt], 0, 0, 0);
            }
        }
#pragma unroll
        for (int nt = 0; nt < 2; ++nt) {
            const int cc = nhalf * 32 + nt * 16 + m;
#pragma unroll
            for (int r = 0; r < 4; ++r) {
                const size_t off = (size_t)(row0 + quad * 4 + r) * 64 + cc;
                Yl[off] = f2b(accl[nt][r]);
                Yr[off] = f2b(accr[nt][r]);
            }
        }
    }
}

// ---------------- pass A: bucket edges, packed (src<<7)|dstLocal ----------------
__global__ __launch_bounds__(256) void bucket_scatter(const int* __restrict__ src,
                                                      const int* __restrict__ dst,
                                                      int* __restrict__ bcnt,
                                                      int* __restrict__ pairs) {
    const int g = blockIdx.x & (NSUB - 1);
    for (int e = blockIdx.x * 256 + threadIdx.x; e < NE; e += SCAT_BLOCKS * 256) {
        const int s = src[e];
        const int d = dst[e];
        const int b = d >> 7;
        const int pos = atomicAdd(&bcnt[b * NSUB + g], 1);
        if (pos < BCAP)
            pairs[((size_t)(b * NSUB + g)) * BCAP + pos] = (s << 7) | (d & (BNODES - 1));
    }
}

// ---------------- pass B: LDS counting-sort + register-gather + fused epilogue -------
__global__ __launch_bounds__(256) void spmm_sorted(const int* __restrict__ bcnt,
                                                   const int* __restrict__ pairs,
                                                   const ushort* __restrict__ Yl,
                                                   const ushort* __restrict__ Yr,
                                                   const float* __restrict__ bias,
                                                   const float* __restrict__ bng,
                                                   const float* __restrict__ bnb,
                                                   const float* __restrict__ bnm,
                                                   const float* __restrict__ bnv,
                                                   ushort* __restrict__ outp) {
    __shared__ int scol[NSUB * BCAP];   // 16 KB: sorted src ids
    __shared__ int deg[BNODES];
    __shared__ int offs[BNODES];        // inclusive scan of deg
    __shared__ int fill[BNODES];
    __shared__ int slen[NSUB];
    const int tid = threadIdx.x;
    const int b = blockIdx.x;

    if (tid < BNODES) { deg[tid] = 0; fill[tid] = 0; }
    if (tid < NSUB) {
        int l = bcnt[b * NSUB + tid];
        slen[tid] = l > BCAP ? BCAP : l;
    }
    __syncthreads();

    // phase 1: per-dstLocal degree count
    for (int g = 0; g < NSUB; ++g) {
        const int len = slen[g];
        const int* seg = pairs + (size_t)(b * NSUB + g) * BCAP;
        for (int i = tid; i < len; i += 256)
            atomicAdd(&deg[seg[i] & (BNODES - 1)], 1);
    }
    __syncthreads();

    // phase 2: inclusive scan of deg -> offs
    if (tid < BNODES) offs[tid] = deg[tid];
    __syncthreads();
    for (int s = 1; s < BNODES; s <<= 1) {
        int v = 0;
        if (tid < BNODES && tid >= s) v = offs[tid - s];
        __syncthreads();
        if (tid < BNODES) offs[tid] += v;
        __syncthreads();
    }

    // phase 3: scatter src ids into sorted order
    for (int g = 0; g < NSUB; ++g) {
        const int len = slen[g];
        const int* seg = pairs + (size_t)(b * NSUB + g) * BCAP;
        for (int i = tid; i < len; i += 256) {
            const int pv = seg[i];
            const int dl = pv & (BNODES - 1);
            const int pos = (offs[dl] - deg[dl]) + atomicAdd(&fill[dl], 1);
            scol[pos] = pv >> 7;
        }
    }
    __syncthreads();

    // phase 4: gather + mean + bias + root + BN + ReLU
    const int wv = tid >> 6, lane = tid & 63;
    const int grp = lane >> 4, subl = lane & 15;

    const float4 bias4 = *(const float4*)(bias + subl * 4);
    const float4 g4 = *(const float4*)(bng + subl * 4);
    const float4 v4 = *(const float4*)(bnv + subl * 4);
    const float4 m4 = *(const float4*)(bnm + subl * 4);
    const float4 bb4 = *(const float4*)(bnb + subl * 4);
    const float sc0 = g4.x * rsqrtf(v4.x + BN_EPS);
    const float sc1 = g4.y * rsqrtf(v4.y + BN_EPS);
    const float sc2 = g4.z * rsqrtf(v4.z + BN_EPS);
    const float sc3 = g4.w * rsqrtf(v4.w + BN_EPS);

    for (int i = 0; i < 8; ++i) {
        const int nl = wv * 32 + i * 4 + grp;
        const int node = b * BNODES + nl;
        if (node >= NN) continue;
        const int dg = deg[nl];
        const int beg = offs[nl] - dg;
        const int end = beg + dg;
        float a0 = 0.f, a1 = 0.f, a2 = 0.f, a3 = 0.f;
        float c0 = 0.f, c1 = 0.f, c2 = 0.f, c3 = 0.f;
        int e = beg;
        for (; e + 1 < end; e += 2) {
            const int s0 = scol[e];
            const int s1 = scol[e + 1];
            const uint2 r0 = *(const uint2*)(Yl + (size_t)s0 * 64 + subl * 4);
            const uint2 r1 = *(const uint2*)(Yl + (size_t)s1 * 64 + subl * 4);
            a0 += blo(r0.x); a1 += bhi(r0.x); a2 += blo(r0.y); a3 += bhi(r0.y);
            c0 += blo(r1.x); c1 += bhi(r1.x); c2 += blo(r1.y); c3 += bhi(r1.y);
        }
        if (e < end) {
            const int s0 = scol[e];
            const uint2 r0 = *(const uint2*)(Yl + (size_t)s0 * 64 + subl * 4);
            a0 += blo(r0.x); a1 += bhi(r0.x); a2 += blo(r0.y); a3 += bhi(r0.y);
        }
        a0 += c0; a1 += c1; a2 += c2; a3 += c3;
        const float inv = 1.0f / fmaxf((float)dg, 1.0f);
        const uint2 yr = *(const uint2*)(Yr + (size_t)node * 64 + subl * 4);
        const float h0 = a0 * inv + bias4.x + blo(yr.x);
        const float h1 = a1 * inv + bias4.y + bhi(yr.x);
        const float h2 = a2 * inv + bias4.z + blo(yr.y);
        const float h3 = a3 * inv + bias4.w + bhi(yr.y);
        const float o0 = fmaxf((h0 - m4.x) * sc0 + bb4.x, 0.0f);
        const float o1 = fmaxf((h1 - m4.y) * sc1 + bb4.y, 0.0f);
        const float o2 = fmaxf((h2 - m4.z) * sc2 + bb4.z, 0.0f);
        const float o3 = fmaxf((h3 - m4.w) * sc3 + bb4.w, 0.0f);
        uint2 o;
        o.x = (unsigned)f2b(o0) | ((unsigned)f2b(o1) << 16);
        o.y = (unsigned)f2b(o2) | ((unsigned)f2b(o3) << 16);
        *(uint2*)(outp + (size_t)node * 64 + subl * 4) = o;
    }
}

// ---------------- segmented global mean pool: 16 nodes/wave, 6250 waves ----------------
__global__ __launch_bounds__(256) void pool_seg(const ushort* __restrict__ h,
                                                const int* __restrict__ batch,
                                                float* __restrict__ gsum,
                                                float* __restrict__ gcnt) {
    const int wave = blockIdx.x * 4 + (threadIdx.x >> 6);
    const int lane = threadIdx.x & 63;
    const int n0 = wave * PNODES;
    if (n0 >= NN) return;
    const int n1 = (n0 + PNODES < NN) ? n0 + PNODES : NN;
    int g = batch[n0];
    float acc = 0.f, c = 0.f;
#pragma unroll 4
    for (int n = n0; n < n1; ++n) {
        const int b = batch[n];
        if (b != g) {
            atomicAdd(&gsum[g * 64 + lane], acc);
            if (lane == 0) atomicAdd(&gcnt[g], c);
            acc = 0.f; c = 0.f; g = b;
        }
        acc += b2f(h[(size_t)n * 64 + lane]);
        c += 1.0f;
    }
    atomicAdd(&gsum[g * 64 + lane], acc);
    if (lane == 0) atomicAdd(&gcnt[g], c);
}

// ---------------- classifier head ----------------
__global__ __launch_bounds__(64) void head_kernel(const float* __restrict__ gsum,
                                                  const float* __restrict__ gcnt,
                                                  const float* __restrict__ Wc1,
                                                  const float* __restrict__ bc1,
                                                  const float* __restrict__ g3,
                                                  const float* __restrict__ b3,
                                                  const float* __restrict__ m3,
                                                  const float* __restrict__ v3,
                                                  const float* __restrict__ Wc2,
                                                  const float* __restrict__ bc2,
                                                  float* __restrict__ out) {
    __shared__ float sg[64];
    __shared__ float st[64];
    __shared__ float sl[10];
    __shared__ float sls;
    const int b = blockIdx.x;
    const int c = threadIdx.x;
    sg[c] = gsum[b * 64 + c] / fmaxf(gcnt[b], 1.0f);
    __syncthreads();
    float acc = bc1[c];
#pragma unroll
    for (int k = 0; k < 64; ++k) acc += sg[k] * Wc1[k * 64 + c];
    const float sc = g3[c] * rsqrtf(v3[c] + BN_EPS);
    st[c] = fmaxf((acc - m3[c]) * sc + b3[c], 0.0f);
    __syncthreads();
    if (c < CC) {
        float lg = bc2[c];
#pragma unroll
        for (int k = 0; k < 64; ++k) lg += st[k] * Wc2[k * CC + c];
        sl[c] = lg;
    }
    __syncthreads();
    if (c == 0) {
        float mx = sl[0];
        for (int i = 1; i < CC; ++i) mx = fmaxf(mx, sl[i]);
        float s = 0.f;
        for (int i = 0; i < CC; ++i) s += expf(sl[i] - mx);
        sls = mx + logf(s);
    }
    __syncthreads();
    if (c < CC) out[b * CC + c] = sl[c] - sls;
}

extern "C" void kernel_launch(void* const* d_in, const int* in_sizes, int n_in,
                              void* d_out, int out_size, void* d_ws, size_t ws_size,
                              hipStream_t stream) {
    const float* x    = (const float*)d_in[0];
    const int*   ei   = (const int*)d_in[1];
    const int*   batch= (const int*)d_in[2];
    const float* W1l  = (const float*)d_in[3];
    const float* W1r  = (const float*)d_in[4];
    const float* b1   = (const float*)d_in[5];
    const float* W2l  = (const float*)d_in[6];
    const float* W2r  = (const float*)d_in[7];
    const float* b2   = (const float*)d_in[8];
    const float* bn1g = (const float*)d_in[9];
    const float* bn1b = (const float*)d_in[10];
    const float* bn1m = (const float*)d_in[11];
    const float* bn1v = (const float*)d_in[12];
    const float* bn2g = (const float*)d_in[13];
    const float* bn2b = (const float*)d_in[14];
    const float* bn2m = (const float*)d_in[15];
    const float* bn2v = (const float*)d_in[16];
    const float* bn3g = (const float*)d_in[17];
    const float* bn3b = (const float*)d_in[18];
    const float* bn3m = (const float*)d_in[19];
    const float* bn3v = (const float*)d_in[20];
    const float* Wc1  = (const float*)d_in[21];
    const float* bc1  = (const float*)d_in[22];
    const float* Wc2  = (const float*)d_in[23];
    const float* bc2  = (const float*)d_in[24];
    float* out = (float*)d_out;

    const int* src = ei;
    const int* dst = ei + NE;

    // workspace layout (all blocks 16B-aligned)
    char* p = (char*)d_ws;
    ushort* yl   = (ushort*)p;                 p += (size_t)NN * 64 * 2;           // 12.8 MB
    ushort* yr   = (ushort*)p;                 p += (size_t)NN * 64 * 2;           // 12.8 MB
    ushort* hbuf = (ushort*)p;                 p += (size_t)NN * 64 * 2;           // 12.8 MB
    int*    pairs= (int*)p;                    p += (size_t)NB * NSUB * BCAP * 4;  // 12.8 MB
    int*    bcnt = (int*)p;                    p += (size_t)NB * NSUB * 4;         // 25 KB
    ushort* w1ls = (ushort*)p;                 p += (size_t)FF * 64 * 2;
    ushort* w1rs = (ushort*)p;                 p += (size_t)FF * 64 * 2;
    ushort* w2ls = (ushort*)p;                 p += (size_t)HH * 64 * 2;
    ushort* w2rs = (ushort*)p;                 p += (size_t)HH * 64 * 2;
    float* gsum  = (float*)p;                  p += (size_t)GG * 64 * 4;
    float* gcnt  = (float*)p;                  p += (size_t)GG * 4;

    // ---- edge bucketing (once, reused by both layers) ----
    hipMemsetAsync(bcnt, 0, (size_t)NB * NSUB * sizeof(int), stream);
    bucket_scatter<<<SCAT_BLOCKS, 256, 0, stream>>>(src, dst, bcnt, pairs);

    // ---- weight swizzles ----
    w_swizzle<FF><<<((FF / 32) * 256 + 255) / 256, 256, 0, stream>>>(W1l, W1r, w1ls, w1rs);
    w_swizzle<HH><<<((HH / 32) * 256 + 255) / 256, 256, 0, stream>>>(W2l, W2r, w2ls, w2rs);

    // ---- layer 1 ----
    gemm_mfma<FF, 5, true><<<625, 256, 0, stream>>>((const void*)x, w1ls, w1rs, yl, yr);
    spmm_sorted<<<NB, 256, 0, stream>>>(bcnt, pairs, yl, yr, b1,
                                        bn1g, bn1b, bn1m, bn1v, hbuf);

    // ---- layer 2 ----
    gemm_mfma<HH, 5, false><<<625, 256, 0, stream>>>((const void*)hbuf, w2ls, w2rs, yl, yr);
    spmm_sorted<<<NB, 256, 0, stream>>>(bcnt, pairs, yl, yr, b2,
                                        bn2g, bn2b, bn2m, bn2v, hbuf);

    // ---- pool + head ----
    hipMemsetAsync(gsum, 0, (size_t)(GG * 64 + GG) * sizeof(float), stream);
    pool_seg<<<POOL_BLOCKS, 256, 0, stream>>>(hbuf, batch, gsum, gcnt);
    head_kernel<<<GG, 64, 0, stream>>>(gsum, gcnt, Wc1, bc1,
                                       bn3g, bn3b, bn3m, bn3v, Wc2, bc2, out);
}

// Round 8
// 351.349 us; speedup vs baseline: 4.8770x; 1.1170x over previous
//
#include <hip/hip_runtime.h>
#include <hip/hip_bf16.h>
#include <math.h>

#define NN 100000
#define NE 1600000
#define FF 128
#define HH 64
#define CC 10
#define GG 128
#define BN_EPS 1e-5f

// bucketed-edge constants
#define BNODES 128              // nodes per bucket (dst>>7)
#define NB 782                  // ceil(NN/BNODES)
#define PBLK 128                // partition blocks (counting sort)
#define ECHUNK 12500            // NE / PBLK exactly
#define MHIST (NB * PBLK)       // 100096 = 391*256 exactly
#define NB_SCAN 391
#define SCOL_CAP 4096           // max edges/bucket in LDS (mean 2046, +45 sigma)

// pool constants
#define PNODES 16               // nodes per wave in pool
#define POOL_BLOCKS 1563        // ceil(100000/16/4)

typedef short v8bf __attribute__((ext_vector_type(8)));
typedef float v4f  __attribute__((ext_vector_type(4)));

__device__ inline ushort f2b(float x) {
    __hip_bfloat16 h = __float2bfloat16(x);
    return *reinterpret_cast<ushort*>(&h);
}
__device__ inline float b2f(ushort u) {
    return __uint_as_float(((unsigned)u) << 16);
}
__device__ inline float blo(unsigned u) { return __uint_as_float(u << 16); }
__device__ inline float bhi(unsigned u) { return __uint_as_float(u & 0xffff0000u); }

// ---------------- W [K][64] fp32 -> bf16 swizzled into MFMA B-fragment order ----------
template<int K>
__global__ __launch_bounds__(256) void w_swizzle(const float* __restrict__ Wl,
                                                 const float* __restrict__ Wr,
                                                 ushort* __restrict__ ol,
                                                 ushort* __restrict__ orr) {
    constexpr int T = (K / 32) * 4 * 64;
    const int t = blockIdx.x * 256 + threadIdx.x;
    if (t >= T) return;
    const int lane = t & 63, nt = (t >> 6) & 3, ks = t >> 8;
    const int m = lane & 15, quad = lane >> 4;
#pragma unroll
    for (int j = 0; j < 8; ++j) {
        const int kk = ks * 32 + quad * 8 + j;
        const int cc = nt * 16 + m;
        ol[t * 8 + j]  = f2b(Wl[kk * 64 + cc]);
        orr[t * 8 + j] = f2b(Wr[kk * 64 + cc]);
    }
}

// ---------------- dual MFMA GEMM: Yl = X@Wl, Yr = X@Wr (bf16 out) ----------------
template<int K, int TPB, bool AF32>
__global__ __launch_bounds__(256) void gemm_mfma(const void* __restrict__ Xv,
                                                 const ushort* __restrict__ Bl,
                                                 const ushort* __restrict__ Br,
                                                 ushort* __restrict__ Yl,
                                                 ushort* __restrict__ Yr) {
    constexpr int KS = K / 32;
    const int lane  = threadIdx.x & 63;
    const int wave  = threadIdx.x >> 6;
    const int nhalf = wave & 1;
    const int rsub  = wave >> 1;
    const int m = lane & 15, quad = lane >> 4;

    v8bf bl[KS][2], br[KS][2];
#pragma unroll
    for (int ks = 0; ks < KS; ++ks)
#pragma unroll
        for (int nt = 0; nt < 2; ++nt) {
            const int nti = nhalf * 2 + nt;
            bl[ks][nt] = *(const v8bf*)(Bl + ((size_t)(ks * 4 + nti) * 64 + lane) * 8);
            br[ks][nt] = *(const v8bf*)(Br + ((size_t)(ks * 4 + nti) * 64 + lane) * 8);
        }

    for (int it = 0; it < TPB; ++it) {
        const int bt = blockIdx.x * TPB + it;
        const int row0 = bt * 32 + rsub * 16;
        if (row0 >= NN) return;
        const v4f z = {0.f, 0.f, 0.f, 0.f};
        v4f accl[2] = {z, z}, accr[2] = {z, z};
#pragma unroll
        for (int ks = 0; ks < KS; ++ks) {
            v8bf a;
            if (AF32) {
                const float* xrow = (const float*)Xv + (size_t)(row0 + m) * K + quad * 8 + ks * 32;
                const float4 a0 = *(const float4*)(xrow);
                const float4 a1 = *(const float4*)(xrow + 4);
                a[0] = (short)f2b(a0.x); a[1] = (short)f2b(a0.y);
                a[2] = (short)f2b(a0.z); a[3] = (short)f2b(a0.w);
                a[4] = (short)f2b(a1.x); a[5] = (short)f2b(a1.y);
                a[6] = (short)f2b(a1.z); a[7] = (short)f2b(a1.w);
            } else {
                const ushort* xrow = (const ushort*)Xv + (size_t)(row0 + m) * K + quad * 8 + ks * 32;
                a = *(const v8bf*)xrow;
            }
#pragma unroll
            for (int nt = 0; nt < 2; ++nt) {
                accl[nt] = __builtin_amdgcn_mfma_f32_16x16x32_bf16(a, bl[ks][nt], accl[nt], 0, 0, 0);
                accr[nt] = __builtin_amdgcn_mfma_f32_16x16x32_bf16(a, br[ks][nt], accr[nt], 0, 0, 0);
            }
        }
#pragma unroll
        for (int nt = 0; nt < 2; ++nt) {
            const int cc = nhalf * 32 + nt * 16 + m;
#pragma unroll
            for (int r = 0; r < 4; ++r) {
                const size_t off = (size_t)(row0 + quad * 4 + r) * 64 + cc;
                Yl[off] = f2b(accl[nt][r]);
                Yr[off] = f2b(accr[nt][r]);
            }
        }
    }
}

// ---------------- pass A1: per-(block,bucket) histogram ----------------
__global__ __launch_bounds__(256) void edge_hist(const int* __restrict__ dst,
                                                 int* __restrict__ hist) {
    __shared__ int h[NB];
    for (int i = threadIdx.x; i < NB; i += 256) h[i] = 0;
    __syncthreads();
    const int e0 = blockIdx.x * ECHUNK;
    for (int e = e0 + threadIdx.x; e < e0 + ECHUNK; e += 256)
        atomicAdd(&h[dst[e] >> 7], 1);
    __syncthreads();
    for (int i = threadIdx.x; i < NB; i += 256)
        hist[i * PBLK + blockIdx.x] = h[i];   // bucket-major for the scan
}

// ---------------- pass A2: 3-phase exclusive scan over hist[MHIST] ----------------
__global__ __launch_bounds__(256) void scan_block(const int* __restrict__ cnt,
                                                  int* __restrict__ rp,
                                                  int* __restrict__ bsum) {
    __shared__ int s[256];
    const int tid = threadIdx.x;
    const int i = blockIdx.x * 256 + tid;
    const int v = cnt[i];
    s[tid] = v;
    __syncthreads();
    for (int off = 1; off < 256; off <<= 1) {
        int t = (tid >= off) ? s[tid - off] : 0;
        __syncthreads();
        s[tid] += t;
        __syncthreads();
    }
    rp[i] = s[tid] - v;
    if (tid == 255) bsum[blockIdx.x] = s[255];
}

__global__ __launch_bounds__(512) void scan_bsums(int* __restrict__ bsum,
                                                  int* __restrict__ boff,
                                                  int* __restrict__ rp) {
    __shared__ int s[512];
    const int tid = threadIdx.x;
    const int v = (tid < NB_SCAN) ? bsum[tid] : 0;
    s[tid] = v;
    __syncthreads();
    for (int off = 1; off < 512; off <<= 1) {
        int t = (tid >= off) ? s[tid - off] : 0;
        __syncthreads();
        s[tid] += t;
        __syncthreads();
    }
    if (tid < NB_SCAN) boff[tid] = s[tid] - v;
    if (tid == 0) rp[MHIST] = NE;   // sentinel
}

__global__ __launch_bounds__(256) void scan_add(int* __restrict__ rp,
                                                const int* __restrict__ boff) {
    const int i = blockIdx.x * 256 + threadIdx.x;
    rp[i] += boff[blockIdx.x];
}

// ---------------- pass A3: scatter to exact positions (no global atomics) ----------
__global__ __launch_bounds__(256) void edge_scatter(const int* __restrict__ src,
                                                    const int* __restrict__ dst,
                                                    const int* __restrict__ goffs,
                                                    int* __restrict__ pairs) {
    __shared__ int cur[NB];
    for (int i = threadIdx.x; i < NB; i += 256)
        cur[i] = goffs[i * PBLK + blockIdx.x];
    __syncthreads();
    const int e0 = blockIdx.x * ECHUNK;
    for (int e = e0 + threadIdx.x; e < e0 + ECHUNK; e += 256) {
        const int s = src[e];
        const int d = dst[e];
        const int pos = atomicAdd(&cur[d >> 7], 1);
        pairs[pos] = (s << 7) | (d & (BNODES - 1));
    }
}

// ---------------- pass B: LDS counting-sort + register-gather + fused epilogue -------
__global__ __launch_bounds__(256) void spmm_sorted(const int* __restrict__ goffs,
                                                   const int* __restrict__ pairs,
                                                   const ushort* __restrict__ Yl,
                                                   const ushort* __restrict__ Yr,
                                                   const float* __restrict__ bias,
                                                   const float* __restrict__ bng,
                                                   const float* __restrict__ bnb,
                                                   const float* __restrict__ bnm,
                                                   const float* __restrict__ bnv,
                                                   ushort* __restrict__ outp) {
    __shared__ int scol[SCOL_CAP];      // 16 KB: sorted src ids
    __shared__ int deg[BNODES];
    __shared__ int loffs[BNODES];       // inclusive scan of deg
    __shared__ int fill[BNODES];
    const int tid = threadIdx.x;
    const int b = blockIdx.x;

    if (tid < BNODES) { deg[tid] = 0; fill[tid] = 0; }
    __syncthreads();

    const int beg = goffs[b * PBLK];
    int end = goffs[(b + 1) * PBLK];    // b=NB-1 hits the sentinel = NE
    if (end - beg > SCOL_CAP) end = beg + SCOL_CAP;

    // phase 1: per-dstLocal degree count
    for (int i = beg + tid; i < end; i += 256)
        atomicAdd(&deg[pairs[i] & (BNODES - 1)], 1);
    __syncthreads();

    // phase 2: inclusive scan of deg -> loffs
    if (tid < BNODES) loffs[tid] = deg[tid];
    __syncthreads();
    for (int s = 1; s < BNODES; s <<= 1) {
        int v = 0;
        if (tid < BNODES && tid >= s) v = loffs[tid - s];
        __syncthreads();
        if (tid < BNODES) loffs[tid] += v;
        __syncthreads();
    }

    // phase 3: scatter src ids into dst-sorted order
    for (int i = beg + tid; i < end; i += 256) {
        const int pv = pairs[i];
        const int dl = pv & (BNODES - 1);
        const int pos = (loffs[dl] - deg[dl]) + atomicAdd(&fill[dl], 1);
        scol[pos] = pv >> 7;
    }
    __syncthreads();

    // phase 4: gather + mean + bias + root + BN + ReLU
    const int wv = tid >> 6, lane = tid & 63;
    const int grp = lane >> 4, subl = lane & 15;

    const float4 bias4 = *(const float4*)(bias + subl * 4);
    const float4 g4 = *(const float4*)(bng + subl * 4);
    const float4 v4 = *(const float4*)(bnv + subl * 4);
    const float4 m4 = *(const float4*)(bnm + subl * 4);
    const float4 bb4 = *(const float4*)(bnb + subl * 4);
    const float sc0 = g4.x * rsqrtf(v4.x + BN_EPS);
    const float sc1 = g4.y * rsqrtf(v4.y + BN_EPS);
    const float sc2 = g4.z * rsqrtf(v4.z + BN_EPS);
    const float sc3 = g4.w * rsqrtf(v4.w + BN_EPS);

    for (int i = 0; i < 8; ++i) {
        const int nl = wv * 32 + i * 4 + grp;
        const int node = b * BNODES + nl;
        if (node >= NN) continue;
        const int dg = deg[nl];
        const int nbeg = loffs[nl] - dg;
        const int nend = nbeg + dg;
        float a0 = 0.f, a1 = 0.f, a2 = 0.f, a3 = 0.f;
        float c0 = 0.f, c1 = 0.f, c2 = 0.f, c3 = 0.f;
        int e = nbeg;
        for (; e + 1 < nend; e += 2) {
            const int s0 = scol[e];
            const int s1 = scol[e + 1];
            const uint2 r0 = *(const uint2*)(Yl + (size_t)s0 * 64 + subl * 4);
            const uint2 r1 = *(const uint2*)(Yl + (size_t)s1 * 64 + subl * 4);
            a0 += blo(r0.x); a1 += bhi(r0.x); a2 += blo(r0.y); a3 += bhi(r0.y);
            c0 += blo(r1.x); c1 += bhi(r1.x); c2 += blo(r1.y); c3 += bhi(r1.y);
        }
        if (e < nend) {
            const int s0 = scol[e];
            const uint2 r0 = *(const uint2*)(Yl + (size_t)s0 * 64 + subl * 4);
            a0 += blo(r0.x); a1 += bhi(r0.x); a2 += blo(r0.y); a3 += bhi(r0.y);
        }
        a0 += c0; a1 += c1; a2 += c2; a3 += c3;
        const float inv = 1.0f / fmaxf((float)dg, 1.0f);
        const uint2 yr = *(const uint2*)(Yr + (size_t)node * 64 + subl * 4);
        const float h0 = a0 * inv + bias4.x + blo(yr.x);
        const float h1 = a1 * inv + bias4.y + bhi(yr.x);
        const float h2 = a2 * inv + bias4.z + blo(yr.y);
        const float h3 = a3 * inv + bias4.w + bhi(yr.y);
        const float o0 = fmaxf((h0 - m4.x) * sc0 + bb4.x, 0.0f);
        const float o1 = fmaxf((h1 - m4.y) * sc1 + bb4.y, 0.0f);
        const float o2 = fmaxf((h2 - m4.z) * sc2 + bb4.z, 0.0f);
        const float o3 = fmaxf((h3 - m4.w) * sc3 + bb4.w, 0.0f);
        uint2 o;
        o.x = (unsigned)f2b(o0) | ((unsigned)f2b(o1) << 16);
        o.y = (unsigned)f2b(o2) | ((unsigned)f2b(o3) << 16);
        *(uint2*)(outp + (size_t)node * 64 + subl * 4) = o;
    }
}

// ---------------- segmented global mean pool: 16 nodes/wave ----------------
__global__ __launch_bounds__(256) void pool_seg(const ushort* __restrict__ h,
                                                const int* __restrict__ batch,
                                                float* __restrict__ gsum,
                                                float* __restrict__ gcnt) {
    const int wave = blockIdx.x * 4 + (threadIdx.x >> 6);
    const int lane = threadIdx.x & 63;
    const int n0 = wave * PNODES;
    if (n0 >= NN) return;
    const int n1 = (n0 + PNODES < NN) ? n0 + PNODES : NN;
    int g = batch[n0];
    float acc = 0.f, c = 0.f;
#pragma unroll 4
    for (int n = n0; n < n1; ++n) {
        const int b = batch[n];
        if (b != g) {
            atomicAdd(&gsum[g * 64 + lane], acc);
            if (lane == 0) atomicAdd(&gcnt[g], c);
            acc = 0.f; c = 0.f; g = b;
        }
        acc += b2f(h[(size_t)n * 64 + lane]);
        c += 1.0f;
    }
    atomicAdd(&gsum[g * 64 + lane], acc);
    if (lane == 0) atomicAdd(&gcnt[g], c);
}

// ---------------- classifier head ----------------
__global__ __launch_bounds__(64) void head_kernel(const float* __restrict__ gsum,
                                                  const float* __restrict__ gcnt,
                                                  const float* __restrict__ Wc1,
                                                  const float* __restrict__ bc1,
                                                  const float* __restrict__ g3,
                                                  const float* __restrict__ b3,
                                                  const float* __restrict__ m3,
                                                  const float* __restrict__ v3,
                                                  const float* __restrict__ Wc2,
                                                  const float* __restrict__ bc2,
                                                  float* __restrict__ out) {
    __shared__ float sg[64];
    __shared__ float st[64];
    __shared__ float sl[10];
    __shared__ float sls;
    const int b = blockIdx.x;
    const int c = threadIdx.x;
    sg[c] = gsum[b * 64 + c] / fmaxf(gcnt[b], 1.0f);
    __syncthreads();
    float acc = bc1[c];
#pragma unroll
    for (int k = 0; k < 64; ++k) acc += sg[k] * Wc1[k * 64 + c];
    const float sc = g3[c] * rsqrtf(v3[c] + BN_EPS);
    st[c] = fmaxf((acc - m3[c]) * sc + b3[c], 0.0f);
    __syncthreads();
    if (c < CC) {
        float lg = bc2[c];
#pragma unroll
        for (int k = 0; k < 64; ++k) lg += st[k] * Wc2[k * CC + c];
        sl[c] = lg;
    }
    __syncthreads();
    if (c == 0) {
        float mx = sl[0];
        for (int i = 1; i < CC; ++i) mx = fmaxf(mx, sl[i]);
        float s = 0.f;
        for (int i = 0; i < CC; ++i) s += expf(sl[i] - mx);
        sls = mx + logf(s);
    }
    __syncthreads();
    if (c < CC) out[b * CC + c] = sl[c] - sls;
}

extern "C" void kernel_launch(void* const* d_in, const int* in_sizes, int n_in,
                              void* d_out, int out_size, void* d_ws, size_t ws_size,
                              hipStream_t stream) {
    const float* x    = (const float*)d_in[0];
    const int*   ei   = (const int*)d_in[1];
    const int*   batch= (const int*)d_in[2];
    const float* W1l  = (const float*)d_in[3];
    const float* W1r  = (const float*)d_in[4];
    const float* b1   = (const float*)d_in[5];
    const float* W2l  = (const float*)d_in[6];
    const float* W2r  = (const float*)d_in[7];
    const float* b2   = (const float*)d_in[8];
    const float* bn1g = (const float*)d_in[9];
    const float* bn1b = (const float*)d_in[10];
    const float* bn1m = (const float*)d_in[11];
    const float* bn1v = (const float*)d_in[12];
    const float* bn2g = (const float*)d_in[13];
    const float* bn2b = (const float*)d_in[14];
    const float* bn2m = (const float*)d_in[15];
    const float* bn2v = (const float*)d_in[16];
    const float* bn3g = (const float*)d_in[17];
    const float* bn3b = (const float*)d_in[18];
    const float* bn3m = (const float*)d_in[19];
    const float* bn3v = (const float*)d_in[20];
    const float* Wc1  = (const float*)d_in[21];
    const float* bc1  = (const float*)d_in[22];
    const float* Wc2  = (const float*)d_in[23];
    const float* bc2  = (const float*)d_in[24];
    float* out = (float*)d_out;

    const int* src = ei;
    const int* dst = ei + NE;

    // workspace layout (all blocks 16B-aligned)
    char* p = (char*)d_ws;
    ushort* yl   = (ushort*)p;                 p += (size_t)NN * 64 * 2;        // 12.8 MB
    ushort* yr   = (ushort*)p;                 p += (size_t)NN * 64 * 2;        // 12.8 MB
    ushort* hbuf = (ushort*)p;                 p += (size_t)NN * 64 * 2;        // 12.8 MB
    int*    pairs= (int*)p;                    p += (size_t)NE * 4;             // 6.4 MB
    int*    hist = (int*)p;                    p += (size_t)MHIST * 4;          // 400 KB
    int*    goffs= (int*)p;                    p += (size_t)(MHIST + 1) * 4;    // 400 KB
    int*    bsum = (int*)p;                    p += 512 * 4;
    int*    boff = (int*)p;                    p += 512 * 4;
    ushort* w1ls = (ushort*)p;                 p += (size_t)FF * 64 * 2;
    ushort* w1rs = (ushort*)p;                 p += (size_t)FF * 64 * 2;
    ushort* w2ls = (ushort*)p;                 p += (size_t)HH * 64 * 2;
    ushort* w2rs = (ushort*)p;                 p += (size_t)HH * 64 * 2;
    float* gsum  = (float*)p;                  p += (size_t)GG * 64 * 4;
    float* gcnt  = (float*)p;                  p += (size_t)GG * 4;

    // ---- edge counting sort (once, reused by both layers) ----
    edge_hist<<<PBLK, 256, 0, stream>>>(dst, hist);
    scan_block<<<NB_SCAN, 256, 0, stream>>>(hist, goffs, bsum);
    scan_bsums<<<1, 512, 0, stream>>>(bsum, boff, goffs);
    scan_add<<<NB_SCAN, 256, 0, stream>>>(goffs, boff);
    edge_scatter<<<PBLK, 256, 0, stream>>>(src, dst, goffs, pairs);

    // ---- weight swizzles ----
    w_swizzle<FF><<<((FF / 32) * 256 + 255) / 256, 256, 0, stream>>>(W1l, W1r, w1ls, w1rs);
    w_swizzle<HH><<<((HH / 32) * 256 + 255) / 256, 256, 0, stream>>>(W2l, W2r, w2ls, w2rs);

    // ---- layer 1 ----
    gemm_mfma<FF, 5, true><<<625, 256, 0, stream>>>((const void*)x, w1ls, w1rs, yl, yr);
    spmm_sorted<<<NB, 256, 0, stream>>>(goffs, pairs, yl, yr, b1,
                                        bn1g, bn1b, bn1m, bn1v, hbuf);

    // ---- layer 2 ----
    gemm_mfma<HH, 5, false><<<625, 256, 0, stream>>>((const void*)hbuf, w2ls, w2rs, yl, yr);
    spmm_sorted<<<NB, 256, 0, stream>>>(goffs, pairs, yl, yr, b2,
                                        bn2g, bn2b, bn2m, bn2v, hbuf);

    // ---- pool + head ----
    hipMemsetAsync(gsum, 0, (size_t)(GG * 64 + GG) * sizeof(float), stream);
    pool_seg<<<POOL_BLOCKS, 256, 0, stream>>>(hbuf, batch, gsum, gcnt);
    head_kernel<<<GG, 64, 0, stream>>>(gsum, gcnt, Wc1, bc1,
                                       bn3g, bn3b, bn3m, bn3v, Wc2, bc2, out);
}

// Round 9
// 319.844 us; speedup vs baseline: 5.3574x; 1.0985x over previous
//
#include <hip/hip_runtime.h>
#include <hip/hip_bf16.h>
#include <math.h>

#define NN 100000
#define NE 1600000
#define FF 128
#define HH 64
#define CC 10
#define GG 128
#define BN_EPS 1e-5f

// bucketed-edge constants
#define BNODES 64               // nodes per bucket (dst>>6)
#define NB 1563                 // ceil(NN/BNODES)
#define PBLK 128                // partition blocks (counting sort)
#define ECHUNK 12500            // NE / PBLK exactly
#define MHIST (NB * PBLK)       // 200064
#define NSCAN 782               // ceil(MHIST/256)
#define SCOL_CAP 2048           // max edges/bucket in LDS (mean 1024, +32 sigma)

// pool constants
#define PNODES 16               // nodes per wave in pool
#define POOL_BLOCKS 1563        // ceil(100000/16/4)

typedef short v8bf __attribute__((ext_vector_type(8)));
typedef float v4f  __attribute__((ext_vector_type(4)));

__device__ inline ushort f2b(float x) {
    __hip_bfloat16 h = __float2bfloat16(x);
    return *reinterpret_cast<ushort*>(&h);
}
__device__ inline float b2f(ushort u) {
    return __uint_as_float(((unsigned)u) << 16);
}
__device__ inline float blo(unsigned u) { return __uint_as_float(u << 16); }
__device__ inline float bhi(unsigned u) { return __uint_as_float(u & 0xffff0000u); }

// ---------------- W [K][64] fp32 -> bf16 swizzled into MFMA B-fragment order ----------
template<int K>
__global__ __launch_bounds__(256) void w_swizzle(const float* __restrict__ Wl,
                                                 const float* __restrict__ Wr,
                                                 ushort* __restrict__ ol,
                                                 ushort* __restrict__ orr) {
    constexpr int T = (K / 32) * 4 * 64;
    const int t = blockIdx.x * 256 + threadIdx.x;
    if (t >= T) return;
    const int lane = t & 63, nt = (t >> 6) & 3, ks = t >> 8;
    const int m = lane & 15, quad = lane >> 4;
#pragma unroll
    for (int j = 0; j < 8; ++j) {
        const int kk = ks * 32 + quad * 8 + j;
        const int cc = nt * 16 + m;
        ol[t * 8 + j]  = f2b(Wl[kk * 64 + cc]);
        orr[t * 8 + j] = f2b(Wr[kk * 64 + cc]);
    }
}

// ---------------- dual MFMA GEMM: Yl = X@Wl, Yr = X@Wr (bf16 out) ----------------
template<int K, int TPB, bool AF32>
__global__ __launch_bounds__(256) void gemm_mfma(const void* __restrict__ Xv,
                                                 const ushort* __restrict__ Bl,
                                                 const ushort* __restrict__ Br,
                                                 ushort* __restrict__ Yl,
                                                 ushort* __restrict__ Yr) {
    constexpr int KS = K / 32;
    const int lane  = threadIdx.x & 63;
    const int wave  = threadIdx.x >> 6;
    const int nhalf = wave & 1;
    const int rsub  = wave >> 1;
    const int m = lane & 15, quad = lane >> 4;

    v8bf bl[KS][2], br[KS][2];
#pragma unroll
    for (int ks = 0; ks < KS; ++ks)
#pragma unroll
        for (int nt = 0; nt < 2; ++nt) {
            const int nti = nhalf * 2 + nt;
            bl[ks][nt] = *(const v8bf*)(Bl + ((size_t)(ks * 4 + nti) * 64 + lane) * 8);
            br[ks][nt] = *(const v8bf*)(Br + ((size_t)(ks * 4 + nti) * 64 + lane) * 8);
        }

    for (int it = 0; it < TPB; ++it) {
        const int bt = blockIdx.x * TPB + it;
        const int row0 = bt * 32 + rsub * 16;
        if (row0 >= NN) return;
        const v4f z = {0.f, 0.f, 0.f, 0.f};
        v4f accl[2] = {z, z}, accr[2] = {z, z};
#pragma unroll
        for (int ks = 0; ks < KS; ++ks) {
            v8bf a;
            if (AF32) {
                const float* xrow = (const float*)Xv + (size_t)(row0 + m) * K + quad * 8 + ks * 32;
                const float4 a0 = *(const float4*)(xrow);
                const float4 a1 = *(const float4*)(xrow + 4);
                a[0] = (short)f2b(a0.x); a[1] = (short)f2b(a0.y);
                a[2] = (short)f2b(a0.z); a[3] = (short)f2b(a0.w);
                a[4] = (short)f2b(a1.x); a[5] = (short)f2b(a1.y);
                a[6] = (short)f2b(a1.z); a[7] = (short)f2b(a1.w);
            } else {
                const ushort* xrow = (const ushort*)Xv + (size_t)(row0 + m) * K + quad * 8 + ks * 32;
                a = *(const v8bf*)xrow;
            }
#pragma unroll
            for (int nt = 0; nt < 2; ++nt) {
                accl[nt] = __builtin_amdgcn_mfma_f32_16x16x32_bf16(a, bl[ks][nt], accl[nt], 0, 0, 0);
                accr[nt] = __builtin_amdgcn_mfma_f32_16x16x32_bf16(a, br[ks][nt], accr[nt], 0, 0, 0);
            }
        }
#pragma unroll
        for (int nt = 0; nt < 2; ++nt) {
            const int cc = nhalf * 32 + nt * 16 + m;
#pragma unroll
            for (int r = 0; r < 4; ++r) {
                const size_t off = (size_t)(row0 + quad * 4 + r) * 64 + cc;
                Yl[off] = f2b(accl[nt][r]);
                Yr[off] = f2b(accr[nt][r]);
            }
        }
    }
}

// ---------------- pass A1: per-(block,bucket) histogram ----------------
__global__ __launch_bounds__(256) void edge_hist(const int* __restrict__ dst,
                                                 int* __restrict__ hist) {
    __shared__ int h[NB];
    for (int i = threadIdx.x; i < NB; i += 256) h[i] = 0;
    __syncthreads();
    const int e0 = blockIdx.x * ECHUNK;
    for (int e = e0 + threadIdx.x; e < e0 + ECHUNK; e += 256)
        atomicAdd(&h[dst[e] >> 6], 1);
    __syncthreads();
    for (int i = threadIdx.x; i < NB; i += 256)
        hist[i * PBLK + blockIdx.x] = h[i];   // bucket-major for the scan
}

// ---------------- pass A2: 3-phase exclusive scan over hist[MHIST] ----------------
__global__ __launch_bounds__(256) void scan_block(const int* __restrict__ cnt,
                                                  int* __restrict__ rp,
                                                  int* __restrict__ bsum) {
    __shared__ int s[256];
    const int tid = threadIdx.x;
    const int i = blockIdx.x * 256 + tid;
    const int v = (i < MHIST) ? cnt[i] : 0;
    s[tid] = v;
    __syncthreads();
    for (int off = 1; off < 256; off <<= 1) {
        int t = (tid >= off) ? s[tid - off] : 0;
        __syncthreads();
        s[tid] += t;
        __syncthreads();
    }
    if (i < MHIST) rp[i] = s[tid] - v;
    if (tid == 255) bsum[blockIdx.x] = s[255];
}

// scan of NSCAN block sums: 256 threads x 4 elements each
__global__ __launch_bounds__(256) void scan_bsums(const int* __restrict__ bsum,
                                                  int* __restrict__ boff,
                                                  int* __restrict__ rp) {
    __shared__ int s[256];
    const int tid = threadIdx.x;
    int v[4];
    int tot = 0;
#pragma unroll
    for (int j = 0; j < 4; ++j) {
        const int idx = tid * 4 + j;
        v[j] = (idx < NSCAN) ? bsum[idx] : 0;
        tot += v[j];
    }
    s[tid] = tot;
    __syncthreads();
    for (int off = 1; off < 256; off <<= 1) {
        int t = (tid >= off) ? s[tid - off] : 0;
        __syncthreads();
        s[tid] += t;
        __syncthreads();
    }
    int run = s[tid] - tot;   // exclusive base for this thread's 4
#pragma unroll
    for (int j = 0; j < 4; ++j) {
        const int idx = tid * 4 + j;
        if (idx < NSCAN) boff[idx] = run;
        run += v[j];
    }
    if (tid == 0) rp[MHIST] = NE;   // sentinel
}

__global__ __launch_bounds__(256) void scan_add(int* __restrict__ rp,
                                                const int* __restrict__ boff) {
    const int i = blockIdx.x * 256 + threadIdx.x;
    if (i < MHIST) rp[i] += boff[blockIdx.x];
}

// ---------------- pass A3: scatter to exact positions (no global atomics) ----------
__global__ __launch_bounds__(256) void edge_scatter(const int* __restrict__ src,
                                                    const int* __restrict__ dst,
                                                    const int* __restrict__ goffs,
                                                    int* __restrict__ pairs) {
    __shared__ int cur[NB];
    for (int i = threadIdx.x; i < NB; i += 256)
        cur[i] = goffs[i * PBLK + blockIdx.x];
    __syncthreads();
    const int e0 = blockIdx.x * ECHUNK;
    for (int e = e0 + threadIdx.x; e < e0 + ECHUNK; e += 256) {
        const int s = src[e];
        const int d = dst[e];
        const int pos = atomicAdd(&cur[d >> 6], 1);
        pairs[pos] = (s << 6) | (d & (BNODES - 1));
    }
}

// ---------------- pass B: LDS counting-sort + register-gather + fused epilogue -------
__global__ __launch_bounds__(256) void spmm_sorted(const int* __restrict__ goffs,
                                                   const int* __restrict__ pairs,
                                                   const ushort* __restrict__ Yl,
                                                   const ushort* __restrict__ Yr,
                                                   const float* __restrict__ bias,
                                                   const float* __restrict__ bng,
                                                   const float* __restrict__ bnb,
                                                   const float* __restrict__ bnm,
                                                   const float* __restrict__ bnv,
                                                   ushort* __restrict__ outp) {
    __shared__ int scol[SCOL_CAP];      // 8 KB: sorted src ids
    __shared__ int deg[BNODES];
    __shared__ int loffs[BNODES];       // inclusive scan of deg
    __shared__ int fill[BNODES];
    const int tid = threadIdx.x;
    const int b = blockIdx.x;

    if (tid < BNODES) { deg[tid] = 0; fill[tid] = 0; }
    __syncthreads();

    const int beg = goffs[b * PBLK];
    int end = goffs[(b + 1) * PBLK];    // b=NB-1 hits the sentinel = NE
    if (end - beg > SCOL_CAP) end = beg + SCOL_CAP;

    // phase 1: per-dstLocal degree count
    for (int i = beg + tid; i < end; i += 256)
        atomicAdd(&deg[pairs[i] & (BNODES - 1)], 1);
    __syncthreads();

    // phase 2: inclusive scan of deg -> loffs
    if (tid < BNODES) loffs[tid] = deg[tid];
    __syncthreads();
    for (int s = 1; s < BNODES; s <<= 1) {
        int v = 0;
        if (tid < BNODES && tid >= s) v = loffs[tid - s];
        __syncthreads();
        if (tid < BNODES) loffs[tid] += v;
        __syncthreads();
    }

    // phase 3: scatter src ids into dst-sorted order
    for (int i = beg + tid; i < end; i += 256) {
        const int pv = pairs[i];
        const int dl = pv & (BNODES - 1);
        const int pos = (loffs[dl] - deg[dl]) + atomicAdd(&fill[dl], 1);
        scol[pos] = pv >> 6;
    }
    __syncthreads();

    // phase 4: gather + mean + bias + root + BN + ReLU
    const int wv = tid >> 6, lane = tid & 63;
    const int grp = lane >> 4, subl = lane & 15;

    const float4 bias4 = *(const float4*)(bias + subl * 4);
    const float4 g4 = *(const float4*)(bng + subl * 4);
    const float4 v4 = *(const float4*)(bnv + subl * 4);
    const float4 m4 = *(const float4*)(bnm + subl * 4);
    const float4 bb4 = *(const float4*)(bnb + subl * 4);
    const float sc0 = g4.x * rsqrtf(v4.x + BN_EPS);
    const float sc1 = g4.y * rsqrtf(v4.y + BN_EPS);
    const float sc2 = g4.z * rsqrtf(v4.z + BN_EPS);
    const float sc3 = g4.w * rsqrtf(v4.w + BN_EPS);

    for (int i = 0; i < 4; ++i) {
        const int nl = wv * 16 + i * 4 + grp;
        const int node = b * BNODES + nl;
        if (node >= NN) continue;
        const int dg = deg[nl];
        const int nbeg = loffs[nl] - dg;
        const int nend = nbeg + dg;
        float a0 = 0.f, a1 = 0.f, a2 = 0.f, a3 = 0.f;
        float c0 = 0.f, c1 = 0.f, c2 = 0.f, c3 = 0.f;
        int e = nbeg;
        for (; e + 1 < nend; e += 2) {
            const int s0 = scol[e];
            const int s1 = scol[e + 1];
            const uint2 r0 = *(const uint2*)(Yl + (size_t)s0 * 64 + subl * 4);
            const uint2 r1 = *(const uint2*)(Yl + (size_t)s1 * 64 + subl * 4);
            a0 += blo(r0.x); a1 += bhi(r0.x); a2 += blo(r0.y); a3 += bhi(r0.y);
            c0 += blo(r1.x); c1 += bhi(r1.x); c2 += blo(r1.y); c3 += bhi(r1.y);
        }
        if (e < nend) {
            const int s0 = scol[e];
            const uint2 r0 = *(const uint2*)(Yl + (size_t)s0 * 64 + subl * 4);
            a0 += blo(r0.x); a1 += bhi(r0.x); a2 += blo(r0.y); a3 += bhi(r0.y);
        }
        a0 += c0; a1 += c1; a2 += c2; a3 += c3;
        const float inv = 1.0f / fmaxf((float)dg, 1.0f);
        const uint2 yr = *(const uint2*)(Yr + (size_t)node * 64 + subl * 4);
        const float h0 = a0 * inv + bias4.x + blo(yr.x);
        const float h1 = a1 * inv + bias4.y + bhi(yr.x);
        const float h2 = a2 * inv + bias4.z + blo(yr.y);
        const float h3 = a3 * inv + bias4.w + bhi(yr.y);
        const float o0 = fmaxf((h0 - m4.x) * sc0 + bb4.x, 0.0f);
        const float o1 = fmaxf((h1 - m4.y) * sc1 + bb4.y, 0.0f);
        const float o2 = fmaxf((h2 - m4.z) * sc2 + bb4.z, 0.0f);
        const float o3 = fmaxf((h3 - m4.w) * sc3 + bb4.w, 0.0f);
        uint2 o;
        o.x = (unsigned)f2b(o0) | ((unsigned)f2b(o1) << 16);
        o.y = (unsigned)f2b(o2) | ((unsigned)f2b(o3) << 16);
        *(uint2*)(outp + (size_t)node * 64 + subl * 4) = o;
    }
}

// ---------------- segmented global mean pool: 16 nodes/wave ----------------
__global__ __launch_bounds__(256) void pool_seg(const ushort* __restrict__ h,
                                                const int* __restrict__ batch,
                                                float* __restrict__ gsum,
                                                float* __restrict__ gcnt) {
    const int wave = blockIdx.x * 4 + (threadIdx.x >> 6);
    const int lane = threadIdx.x & 63;
    const int n0 = wave * PNODES;
    if (n0 >= NN) return;
    const int n1 = (n0 + PNODES < NN) ? n0 + PNODES : NN;
    int g = batch[n0];
    float acc = 0.f, c = 0.f;
#pragma unroll 4
    for (int n = n0; n < n1; ++n) {
        const int b = batch[n];
        if (b != g) {
            atomicAdd(&gsum[g * 64 + lane], acc);
            if (lane == 0) atomicAdd(&gcnt[g], c);
            acc = 0.f; c = 0.f; g = b;
        }
        acc += b2f(h[(size_t)n * 64 + lane]);
        c += 1.0f;
    }
    atomicAdd(&gsum[g * 64 + lane], acc);
    if (lane == 0) atomicAdd(&gcnt[g], c);
}

// ---------------- classifier head ----------------
__global__ __launch_bounds__(64) void head_kernel(const float* __restrict__ gsum,
                                                  const float* __restrict__ gcnt,
                                                  const float* __restrict__ Wc1,
                                                  const float* __restrict__ bc1,
                                                  const float* __restrict__ g3,
                                                  const float* __restrict__ b3,
                                                  const float* __restrict__ m3,
                                                  const float* __restrict__ v3,
                                                  const float* __restrict__ Wc2,
                                                  const float* __restrict__ bc2,
                                                  float* __restrict__ out) {
    __shared__ float sg[64];
    __shared__ float st[64];
    __shared__ float sl[10];
    __shared__ float sls;
    const int b = blockIdx.x;
    const int c = threadIdx.x;
    sg[c] = gsum[b * 64 + c] / fmaxf(gcnt[b], 1.0f);
    __syncthreads();
    float acc = bc1[c];
#pragma unroll
    for (int k = 0; k < 64; ++k) acc += sg[k] * Wc1[k * 64 + c];
    const float sc = g3[c] * rsqrtf(v3[c] + BN_EPS);
    st[c] = fmaxf((acc - m3[c]) * sc + b3[c], 0.0f);
    __syncthreads();
    if (c < CC) {
        float lg = bc2[c];
#pragma unroll
        for (int k = 0; k < 64; ++k) lg += st[k] * Wc2[k * CC + c];
        sl[c] = lg;
    }
    __syncthreads();
    if (c == 0) {
        float mx = sl[0];
        for (int i = 1; i < CC; ++i) mx = fmaxf(mx, sl[i]);
        float s = 0.f;
        for (int i = 0; i < CC; ++i) s += expf(sl[i] - mx);
        sls = mx + logf(s);
    }
    __syncthreads();
    if (c < CC) out[b * CC + c] = sl[c] - sls;
}

extern "C" void kernel_launch(void* const* d_in, const int* in_sizes, int n_in,
                              void* d_out, int out_size, void* d_ws, size_t ws_size,
                              hipStream_t stream) {
    const float* x    = (const float*)d_in[0];
    const int*   ei   = (const int*)d_in[1];
    const int*   batch= (const int*)d_in[2];
    const float* W1l  = (const float*)d_in[3];
    const float* W1r  = (const float*)d_in[4];
    const float* b1   = (const float*)d_in[5];
    const float* W2l  = (const float*)d_in[6];
    const float* W2r  = (const float*)d_in[7];
    const float* b2   = (const float*)d_in[8];
    const float* bn1g = (const float*)d_in[9];
    const float* bn1b = (const float*)d_in[10];
    const float* bn1m = (const float*)d_in[11];
    const float* bn1v = (const float*)d_in[12];
    const float* bn2g = (const float*)d_in[13];
    const float* bn2b = (const float*)d_in[14];
    const float* bn2m = (const float*)d_in[15];
    const float* bn2v = (const float*)d_in[16];
    const float* bn3g = (const float*)d_in[17];
    const float* bn3b = (const float*)d_in[18];
    const float* bn3m = (const float*)d_in[19];
    const float* bn3v = (const float*)d_in[20];
    const float* Wc1  = (const float*)d_in[21];
    const float* bc1  = (const float*)d_in[22];
    const float* Wc2  = (const float*)d_in[23];
    const float* bc2  = (const float*)d_in[24];
    float* out = (float*)d_out;

    const int* src = ei;
    const int* dst = ei + NE;

    // workspace layout (all blocks 16B-aligned)
    char* p = (char*)d_ws;
    ushort* yl   = (ushort*)p;                 p += (size_t)NN * 64 * 2;        // 12.8 MB
    ushort* yr   = (ushort*)p;                 p += (size_t)NN * 64 * 2;        // 12.8 MB
    ushort* hbuf = (ushort*)p;                 p += (size_t)NN * 64 * 2;        // 12.8 MB
    int*    pairs= (int*)p;                    p += (size_t)NE * 4;             // 6.4 MB
    int*    hist = (int*)p;                    p += (size_t)MHIST * 4;          // 800 KB
    int*    goffs= (int*)p;                    p += (size_t)(MHIST + 1) * 4;    // 800 KB
    int*    bsum = (int*)p;                    p += 1024 * 4;
    int*    boff = (int*)p;                    p += 1024 * 4;
    ushort* w1ls = (ushort*)p;                 p += (size_t)FF * 64 * 2;
    ushort* w1rs = (ushort*)p;                 p += (size_t)FF * 64 * 2;
    ushort* w2ls = (ushort*)p;                 p += (size_t)HH * 64 * 2;
    ushort* w2rs = (ushort*)p;                 p += (size_t)HH * 64 * 2;
    float* gsum  = (float*)p;                  p += (size_t)GG * 64 * 4;
    float* gcnt  = (float*)p;                  p += (size_t)GG * 4;

    // ---- edge counting sort (once, reused by both layers) ----
    edge_hist<<<PBLK, 256, 0, stream>>>(dst, hist);
    scan_block<<<NSCAN, 256, 0, stream>>>(hist, goffs, bsum);
    scan_bsums<<<1, 256, 0, stream>>>(bsum, boff, goffs);
    scan_add<<<NSCAN, 256, 0, stream>>>(goffs, boff);
    edge_scatter<<<PBLK, 256, 0, stream>>>(src, dst, goffs, pairs);

    // ---- weight swizzles ----
    w_swizzle<FF><<<((FF / 32) * 256 + 255) / 256, 256, 0, stream>>>(W1l, W1r, w1ls, w1rs);
    w_swizzle<HH><<<((HH / 32) * 256 + 255) / 256, 256, 0, stream>>>(W2l, W2r, w2ls, w2rs);

    // ---- layer 1 ----
    gemm_mfma<FF, 5, true><<<625, 256, 0, stream>>>((const void*)x, w1ls, w1rs, yl, yr);
    spmm_sorted<<<NB, 256, 0, stream>>>(goffs, pairs, yl, yr, b1,
                                        bn1g, bn1b, bn1m, bn1v, hbuf);

    // ---- layer 2 ----
    gemm_mfma<HH, 5, false><<<625, 256, 0, stream>>>((const void*)hbuf, w2ls, w2rs, yl, yr);
    spmm_sorted<<<NB, 256, 0, stream>>>(goffs, pairs, yl, yr, b2,
                                        bn2g, bn2b, bn2m, bn2v, hbuf);

    // ---- pool + head ----
    hipMemsetAsync(gsum, 0, (size_t)(GG * 64 + GG) * sizeof(float), stream);
    pool_seg<<<POOL_BLOCKS, 256, 0, stream>>>(hbuf, batch, gsum, gcnt);
    head_kernel<<<GG, 64, 0, stream>>>(gsum, gcnt, Wc1, bc1,
                                       bn3g, bn3b, bn3m, bn3v, Wc2, bc2, out);
}

// Round 10
// 307.031 us; speedup vs baseline: 5.5810x; 1.0417x over previous
//
#include <hip/hip_runtime.h>
#include <hip/hip_bf16.h>
#include <math.h>

#define NN 100000
#define NE 1600000
#define FF 128
#define HH 64
#define CC 10
#define GG 128
#define BN_EPS 1e-5f

// bucketed-edge constants
#define BNODES 64               // nodes per bucket (dst>>6)
#define NB 1563                 // ceil(NN/BNODES)
#define PBLK 128                // partition blocks (counting sort)
#define ECHUNK 12500            // NE / PBLK exactly
#define MHIST (NB * PBLK)       // 200064
#define NSCAN 782               // ceil(MHIST/256)
#define SCOL_CAP 2048           // max edges/bucket in LDS (mean 1024, +32 sigma)

// pool constants
#define PNODES 16               // nodes per wave in pool
#define POOL_BLOCKS 1563        // ceil(100000/16/4)

typedef short v8bf __attribute__((ext_vector_type(8)));
typedef float v4f  __attribute__((ext_vector_type(4)));

__device__ inline ushort f2b(float x) {
    __hip_bfloat16 h = __float2bfloat16(x);
    return *reinterpret_cast<ushort*>(&h);
}
__device__ inline float b2f(ushort u) {
    return __uint_as_float(((unsigned)u) << 16);
}
__device__ inline float blo(unsigned u) { return __uint_as_float(u << 16); }
__device__ inline float bhi(unsigned u) { return __uint_as_float(u & 0xffff0000u); }

// ---------------- W [K][64] fp32 -> bf16 swizzled into MFMA B-fragment order ----------
template<int K>
__global__ __launch_bounds__(256) void w_swizzle(const float* __restrict__ Wl,
                                                 const float* __restrict__ Wr,
                                                 ushort* __restrict__ ol,
                                                 ushort* __restrict__ orr) {
    constexpr int T = (K / 32) * 4 * 64;
    const int t = blockIdx.x * 256 + threadIdx.x;
    if (t >= T) return;
    const int lane = t & 63, nt = (t >> 6) & 3, ks = t >> 8;
    const int m = lane & 15, quad = lane >> 4;
#pragma unroll
    for (int j = 0; j < 8; ++j) {
        const int kk = ks * 32 + quad * 8 + j;
        const int cc = nt * 16 + m;
        ol[t * 8 + j]  = f2b(Wl[kk * 64 + cc]);
        orr[t * 8 + j] = f2b(Wr[kk * 64 + cc]);
    }
}

// ---------------- dual MFMA GEMM: Yl = X@Wl, Yr = X@Wr (bf16 out) ----------------
template<int K, int TPB, bool AF32>
__global__ __launch_bounds__(256) void gemm_mfma(const void* __restrict__ Xv,
                                                 const ushort* __restrict__ Bl,
                                                 const ushort* __restrict__ Br,
                                                 ushort* __restrict__ Yl,
                                                 ushort* __restrict__ Yr) {
    constexpr int KS = K / 32;
    const int lane  = threadIdx.x & 63;
    const int wave  = threadIdx.x >> 6;
    const int nhalf = wave & 1;
    const int rsub  = wave >> 1;
    const int m = lane & 15, quad = lane >> 4;

    v8bf bl[KS][2], br[KS][2];
#pragma unroll
    for (int ks = 0; ks < KS; ++ks)
#pragma unroll
        for (int nt = 0; nt < 2; ++nt) {
            const int nti = nhalf * 2 + nt;
            bl[ks][nt] = *(const v8bf*)(Bl + ((size_t)(ks * 4 + nti) * 64 + lane) * 8);
            br[ks][nt] = *(const v8bf*)(Br + ((size_t)(ks * 4 + nti) * 64 + lane) * 8);
        }

    for (int it = 0; it < TPB; ++it) {
        const int bt = blockIdx.x * TPB + it;
        const int row0 = bt * 32 + rsub * 16;
        if (row0 >= NN) return;
        const v4f z = {0.f, 0.f, 0.f, 0.f};
        v4f accl[2] = {z, z}, accr[2] = {z, z};
#pragma unroll
        for (int ks = 0; ks < KS; ++ks) {
            v8bf a;
            if (AF32) {
                const float* xrow = (const float*)Xv + (size_t)(row0 + m) * K + quad * 8 + ks * 32;
                const float4 a0 = *(const float4*)(xrow);
                const float4 a1 = *(const float4*)(xrow + 4);
                a[0] = (short)f2b(a0.x); a[1] = (short)f2b(a0.y);
                a[2] = (short)f2b(a0.z); a[3] = (short)f2b(a0.w);
                a[4] = (short)f2b(a1.x); a[5] = (short)f2b(a1.y);
                a[6] = (short)f2b(a1.z); a[7] = (short)f2b(a1.w);
            } else {
                const ushort* xrow = (const ushort*)Xv + (size_t)(row0 + m) * K + quad * 8 + ks * 32;
                a = *(const v8bf*)xrow;
            }
#pragma unroll
            for (int nt = 0; nt < 2; ++nt) {
                accl[nt] = __builtin_amdgcn_mfma_f32_16x16x32_bf16(a, bl[ks][nt], accl[nt], 0, 0, 0);
                accr[nt] = __builtin_amdgcn_mfma_f32_16x16x32_bf16(a, br[ks][nt], accr[nt], 0, 0, 0);
            }
        }
#pragma unroll
        for (int nt = 0; nt < 2; ++nt) {
            const int cc = nhalf * 32 + nt * 16 + m;
#pragma unroll
            for (int r = 0; r < 4; ++r) {
                const size_t off = (size_t)(row0 + quad * 4 + r) * 64 + cc;
                Yl[off] = f2b(accl[nt][r]);
                Yr[off] = f2b(accr[nt][r]);
            }
        }
    }
}

// ---------------- pass A1: per-(block,bucket) histogram (1024 threads) ----------------
__global__ __launch_bounds__(1024) void edge_hist(const int* __restrict__ dst,
                                                  int* __restrict__ hist) {
    __shared__ int h[NB];
    for (int i = threadIdx.x; i < NB; i += 1024) h[i] = 0;
    __syncthreads();
    const int e0 = blockIdx.x * ECHUNK;
    for (int e = e0 + threadIdx.x; e < e0 + ECHUNK; e += 1024)
        atomicAdd(&h[dst[e] >> 6], 1);
    __syncthreads();
    for (int i = threadIdx.x; i < NB; i += 1024)
        hist[i * PBLK + blockIdx.x] = h[i];   // bucket-major for the scan
}

// ---------------- pass A2: 3-phase exclusive scan over hist[MHIST] ----------------
__global__ __launch_bounds__(256) void scan_block(const int* __restrict__ cnt,
                                                  int* __restrict__ rp,
                                                  int* __restrict__ bsum) {
    __shared__ int s[256];
    const int tid = threadIdx.x;
    const int i = blockIdx.x * 256 + tid;
    const int v = (i < MHIST) ? cnt[i] : 0;
    s[tid] = v;
    __syncthreads();
    for (int off = 1; off < 256; off <<= 1) {
        int t = (tid >= off) ? s[tid - off] : 0;
        __syncthreads();
        s[tid] += t;
        __syncthreads();
    }
    if (i < MHIST) rp[i] = s[tid] - v;
    if (tid == 255) bsum[blockIdx.x] = s[255];
}

// scan of NSCAN block sums: 256 threads x 4 elements each
__global__ __launch_bounds__(256) void scan_bsums(const int* __restrict__ bsum,
                                                  int* __restrict__ boff,
                                                  int* __restrict__ rp) {
    __shared__ int s[256];
    const int tid = threadIdx.x;
    int v[4];
    int tot = 0;
#pragma unroll
    for (int j = 0; j < 4; ++j) {
        const int idx = tid * 4 + j;
        v[j] = (idx < NSCAN) ? bsum[idx] : 0;
        tot += v[j];
    }
    s[tid] = tot;
    __syncthreads();
    for (int off = 1; off < 256; off <<= 1) {
        int t = (tid >= off) ? s[tid - off] : 0;
        __syncthreads();
        s[tid] += t;
        __syncthreads();
    }
    int run = s[tid] - tot;   // exclusive base for this thread's 4
#pragma unroll
    for (int j = 0; j < 4; ++j) {
        const int idx = tid * 4 + j;
        if (idx < NSCAN) boff[idx] = run;
        run += v[j];
    }
    if (tid == 0) rp[MHIST] = NE;   // sentinel
}

__global__ __launch_bounds__(256) void scan_add(int* __restrict__ rp,
                                                const int* __restrict__ boff) {
    const int i = blockIdx.x * 256 + threadIdx.x;
    if (i < MHIST) rp[i] += boff[blockIdx.x];
}

// ---------------- pass A3: scatter to exact positions (1024 threads) ----------
__global__ __launch_bounds__(1024) void edge_scatter(const int* __restrict__ src,
                                                     const int* __restrict__ dst,
                                                     const int* __restrict__ goffs,
                                                     int* __restrict__ pairs) {
    __shared__ int cur[NB];
    for (int i = threadIdx.x; i < NB; i += 1024)
        cur[i] = goffs[i * PBLK + blockIdx.x];
    __syncthreads();
    const int e0 = blockIdx.x * ECHUNK;
    for (int e = e0 + threadIdx.x; e < e0 + ECHUNK; e += 1024) {
        const int s = src[e];
        const int d = dst[e];
        const int pos = atomicAdd(&cur[d >> 6], 1);
        pairs[pos] = (s << 6) | (d & (BNODES - 1));
    }
}

// ---------------- pass B: LDS counting-sort + register-gather + fused epilogue -------
__global__ __launch_bounds__(256) void spmm_sorted(const int* __restrict__ goffs,
                                                   const int* __restrict__ pairs,
                                                   const ushort* __restrict__ Yl,
                                                   const ushort* __restrict__ Yr,
                                                   const float* __restrict__ bias,
                                                   const float* __restrict__ bng,
                                                   const float* __restrict__ bnb,
                                                   const float* __restrict__ bnm,
                                                   const float* __restrict__ bnv,
                                                   ushort* __restrict__ outp) {
    __shared__ int scol[SCOL_CAP];      // 8 KB: sorted src ids
    __shared__ int deg[BNODES];
    __shared__ int loffs[BNODES];       // inclusive scan of deg
    __shared__ int fill[BNODES];
    const int tid = threadIdx.x;
    const int b = blockIdx.x;

    if (tid < BNODES) { deg[tid] = 0; fill[tid] = 0; }
    __syncthreads();

    const int beg = goffs[b * PBLK];
    int end = goffs[(b + 1) * PBLK];    // b=NB-1 hits the sentinel = NE
    if (end - beg > SCOL_CAP) end = beg + SCOL_CAP;

    // phase 1: per-dstLocal degree count
    for (int i = beg + tid; i < end; i += 256)
        atomicAdd(&deg[pairs[i] & (BNODES - 1)], 1);
    __syncthreads();

    // phase 2: inclusive scan of deg -> loffs
    if (tid < BNODES) loffs[tid] = deg[tid];
    __syncthreads();
    for (int s = 1; s < BNODES; s <<= 1) {
        int v = 0;
        if (tid < BNODES && tid >= s) v = loffs[tid - s];
        __syncthreads();
        if (tid < BNODES) loffs[tid] += v;
        __syncthreads();
    }

    // phase 3: scatter src ids into dst-sorted order
    for (int i = beg + tid; i < end; i += 256) {
        const int pv = pairs[i];
        const int dl = pv & (BNODES - 1);
        const int pos = (loffs[dl] - deg[dl]) + atomicAdd(&fill[dl], 1);
        scol[pos] = pv >> 6;
    }
    __syncthreads();

    // phase 4: gather + mean + bias + root + BN + ReLU
    const int wv = tid >> 6, lane = tid & 63;
    const int grp = lane >> 4, subl = lane & 15;

    const float4 bias4 = *(const float4*)(bias + subl * 4);
    const float4 g4 = *(const float4*)(bng + subl * 4);
    const float4 v4 = *(const float4*)(bnv + subl * 4);
    const float4 m4 = *(const float4*)(bnm + subl * 4);
    const float4 bb4 = *(const float4*)(bnb + subl * 4);
    const float sc0 = g4.x * rsqrtf(v4.x + BN_EPS);
    const float sc1 = g4.y * rsqrtf(v4.y + BN_EPS);
    const float sc2 = g4.z * rsqrtf(v4.z + BN_EPS);
    const float sc3 = g4.w * rsqrtf(v4.w + BN_EPS);

    for (int i = 0; i < 4; ++i) {
        const int nl = wv * 16 + i * 4 + grp;
        const int node = b * BNODES + nl;
        if (node >= NN) continue;
        const int dg = deg[nl];
        const int nbeg = loffs[nl] - dg;
        const int nend = nbeg + dg;
        float a0 = 0.f, a1 = 0.f, a2 = 0.f, a3 = 0.f;
        float c0 = 0.f, c1 = 0.f, c2 = 0.f, c3 = 0.f;
        int e = nbeg;
        for (; e + 1 < nend; e += 2) {
            const int s0 = scol[e];
            const int s1 = scol[e + 1];
            const uint2 r0 = *(const uint2*)(Yl + (size_t)s0 * 64 + subl * 4);
            const uint2 r1 = *(const uint2*)(Yl + (size_t)s1 * 64 + subl * 4);
            a0 += blo(r0.x); a1 += bhi(r0.x); a2 += blo(r0.y); a3 += bhi(r0.y);
            c0 += blo(r1.x); c1 += bhi(r1.x); c2 += blo(r1.y); c3 += bhi(r1.y);
        }
        if (e < nend) {
            const int s0 = scol[e];
            const uint2 r0 = *(const uint2*)(Yl + (size_t)s0 * 64 + subl * 4);
            a0 += blo(r0.x); a1 += bhi(r0.x); a2 += blo(r0.y); a3 += bhi(r0.y);
        }
        a0 += c0; a1 += c1; a2 += c2; a3 += c3;
        const float inv = 1.0f / fmaxf((float)dg, 1.0f);
        const uint2 yr = *(const uint2*)(Yr + (size_t)node * 64 + subl * 4);
        const float h0 = a0 * inv + bias4.x + blo(yr.x);
        const float h1 = a1 * inv + bias4.y + bhi(yr.x);
        const float h2 = a2 * inv + bias4.z + blo(yr.y);
        const float h3 = a3 * inv + bias4.w + bhi(yr.y);
        const float o0 = fmaxf((h0 - m4.x) * sc0 + bb4.x, 0.0f);
        const float o1 = fmaxf((h1 - m4.y) * sc1 + bb4.y, 0.0f);
        const float o2 = fmaxf((h2 - m4.z) * sc2 + bb4.z, 0.0f);
        const float o3 = fmaxf((h3 - m4.w) * sc3 + bb4.w, 0.0f);
        uint2 o;
        o.x = (unsigned)f2b(o0) | ((unsigned)f2b(o1) << 16);
        o.y = (unsigned)f2b(o2) | ((unsigned)f2b(o3) << 16);
        *(uint2*)(outp + (size_t)node * 64 + subl * 4) = o;
    }
}

// ---------------- segmented global mean pool: 16 nodes/wave ----------------
__global__ __launch_bounds__(256) void pool_seg(const ushort* __restrict__ h,
                                                const int* __restrict__ batch,
                                                float* __restrict__ gsum,
                                                float* __restrict__ gcnt) {
    const int wave = blockIdx.x * 4 + (threadIdx.x >> 6);
    const int lane = threadIdx.x & 63;
    const int n0 = wave * PNODES;
    if (n0 >= NN) return;
    const int n1 = (n0 + PNODES < NN) ? n0 + PNODES : NN;
    int g = batch[n0];
    float acc = 0.f, c = 0.f;
#pragma unroll 4
    for (int n = n0; n < n1; ++n) {
        const int b = batch[n];
        if (b != g) {
            atomicAdd(&gsum[g * 64 + lane], acc);
            if (lane == 0) atomicAdd(&gcnt[g], c);
            acc = 0.f; c = 0.f; g = b;
        }
        acc += b2f(h[(size_t)n * 64 + lane]);
        c += 1.0f;
    }
    atomicAdd(&gsum[g * 64 + lane], acc);
    if (lane == 0) atomicAdd(&gcnt[g], c);
}

// ---------------- classifier head ----------------
__global__ __launch_bounds__(64) void head_kernel(const float* __restrict__ gsum,
                                                  const float* __restrict__ gcnt,
                                                  const float* __restrict__ Wc1,
                                                  const float* __restrict__ bc1,
                                                  const float* __restrict__ g3,
                                                  const float* __restrict__ b3,
                                                  const float* __restrict__ m3,
                                                  const float* __restrict__ v3,
                                                  const float* __restrict__ Wc2,
                                                  const float* __restrict__ bc2,
                                                  float* __restrict__ out) {
    __shared__ float sg[64];
    __shared__ float st[64];
    __shared__ float sl[10];
    __shared__ float sls;
    const int b = blockIdx.x;
    const int c = threadIdx.x;
    sg[c] = gsum[b * 64 + c] / fmaxf(gcnt[b], 1.0f);
    __syncthreads();
    float acc = bc1[c];
#pragma unroll
    for (int k = 0; k < 64; ++k) acc += sg[k] * Wc1[k * 64 + c];
    const float sc = g3[c] * rsqrtf(v3[c] + BN_EPS);
    st[c] = fmaxf((acc - m3[c]) * sc + b3[c], 0.0f);
    __syncthreads();
    if (c < CC) {
        float lg = bc2[c];
#pragma unroll
        for (int k = 0; k < 64; ++k) lg += st[k] * Wc2[k * CC + c];
        sl[c] = lg;
    }
    __syncthreads();
    if (c == 0) {
        float mx = sl[0];
        for (int i = 1; i < CC; ++i) mx = fmaxf(mx, sl[i]);
        float s = 0.f;
        for (int i = 0; i < CC; ++i) s += expf(sl[i] - mx);
        sls = mx + logf(s);
    }
    __syncthreads();
    if (c < CC) out[b * CC + c] = sl[c] - sls;
}

extern "C" void kernel_launch(void* const* d_in, const int* in_sizes, int n_in,
                              void* d_out, int out_size, void* d_ws, size_t ws_size,
                              hipStream_t stream) {
    const float* x    = (const float*)d_in[0];
    const int*   ei   = (const int*)d_in[1];
    const int*   batch= (const int*)d_in[2];
    const float* W1l  = (const float*)d_in[3];
    const float* W1r  = (const float*)d_in[4];
    const float* b1   = (const float*)d_in[5];
    const float* W2l  = (const float*)d_in[6];
    const float* W2r  = (const float*)d_in[7];
    const float* b2   = (const float*)d_in[8];
    const float* bn1g = (const float*)d_in[9];
    const float* bn1b = (const float*)d_in[10];
    const float* bn1m = (const float*)d_in[11];
    const float* bn1v = (const float*)d_in[12];
    const float* bn2g = (const float*)d_in[13];
    const float* bn2b = (const float*)d_in[14];
    const float* bn2m = (const float*)d_in[15];
    const float* bn2v = (const float*)d_in[16];
    const float* bn3g = (const float*)d_in[17];
    const float* bn3b = (const float*)d_in[18];
    const float* bn3m = (const float*)d_in[19];
    const float* bn3v = (const float*)d_in[20];
    const float* Wc1  = (const float*)d_in[21];
    const float* bc1  = (const float*)d_in[22];
    const float* Wc2  = (const float*)d_in[23];
    const float* bc2  = (const float*)d_in[24];
    float* out = (float*)d_out;

    const int* src = ei;
    const int* dst = ei + NE;

    // workspace layout (all blocks 16B-aligned)
    char* p = (char*)d_ws;
    ushort* yl   = (ushort*)p;                 p += (size_t)NN * 64 * 2;        // 12.8 MB
    ushort* yr   = (ushort*)p;                 p += (size_t)NN * 64 * 2;        // 12.8 MB
    ushort* hbuf = (ushort*)p;                 p += (size_t)NN * 64 * 2;        // 12.8 MB
    int*    pairs= (int*)p;                    p += (size_t)NE * 4;             // 6.4 MB
    int*    hist = (int*)p;                    p += (size_t)MHIST * 4;          // 800 KB
    int*    goffs= (int*)p;                    p += (size_t)(MHIST + 1) * 4;    // 800 KB
    int*    bsum = (int*)p;                    p += 1024 * 4;
    int*    boff = (int*)p;                    p += 1024 * 4;
    ushort* w1ls = (ushort*)p;                 p += (size_t)FF * 64 * 2;
    ushort* w1rs = (ushort*)p;                 p += (size_t)FF * 64 * 2;
    ushort* w2ls = (ushort*)p;                 p += (size_t)HH * 64 * 2;
    ushort* w2rs = (ushort*)p;                 p += (size_t)HH * 64 * 2;
    float* gsum  = (float*)p;                  p += (size_t)GG * 64 * 4;
    float* gcnt  = (float*)p;                  p += (size_t)GG * 4;

    // ---- edge counting sort (once, reused by both layers) ----
    edge_hist<<<PBLK, 1024, 0, stream>>>(dst, hist);
    scan_block<<<NSCAN, 256, 0, stream>>>(hist, goffs, bsum);
    scan_bsums<<<1, 256, 0, stream>>>(bsum, boff, goffs);
    scan_add<<<NSCAN, 256, 0, stream>>>(goffs, boff);
    edge_scatter<<<PBLK, 1024, 0, stream>>>(src, dst, goffs, pairs);

    // ---- weight swizzles ----
    w_swizzle<FF><<<((FF / 32) * 256 + 255) / 256, 256, 0, stream>>>(W1l, W1r, w1ls, w1rs);
    w_swizzle<HH><<<((HH / 32) * 256 + 255) / 256, 256, 0, stream>>>(W2l, W2r, w2ls, w2rs);

    // ---- layer 1 ----
    gemm_mfma<FF, 2, true><<<1563, 256, 0, stream>>>((const void*)x, w1ls, w1rs, yl, yr);
    spmm_sorted<<<NB, 256, 0, stream>>>(goffs, pairs, yl, yr, b1,
                                        bn1g, bn1b, bn1m, bn1v, hbuf);

    // ---- layer 2 ----
    gemm_mfma<HH, 2, false><<<1563, 256, 0, stream>>>((const void*)hbuf, w2ls, w2rs, yl, yr);
    spmm_sorted<<<NB, 256, 0, stream>>>(goffs, pairs, yl, yr, b2,
                                        bn2g, bn2b, bn2m, bn2v, hbuf);

    // ---- pool + head ----
    hipMemsetAsync(gsum, 0, (size_t)(GG * 64 + GG) * sizeof(float), stream);
    pool_seg<<<POOL_BLOCKS, 256, 0, stream>>>(hbuf, batch, gsum, gcnt);
    head_kernel<<<GG, 64, 0, stream>>>(gsum, gcnt, Wc1, bc1,
                                       bn3g, bn3b, bn3m, bn3v, Wc2, bc2, out);
}

// Round 11
// 289.435 us; speedup vs baseline: 5.9203x; 1.0608x over previous
//
#include <hip/hip_runtime.h>
#include <hip/hip_bf16.h>
#include <math.h>

#define NN 100000
#define NE 1600000
#define FF 128
#define HH 64
#define CC 10
#define GG 128
#define BN_EPS 1e-5f

// bucketed-edge constants
#define BNODES 64               // nodes per bucket (dst>>6)
#define NB 1563                 // ceil(NN/BNODES)
#define PBLK 128                // partition blocks (counting sort)
#define ECHUNK 12500            // NE / PBLK exactly
#define MHIST (NB * PBLK)       // 200064
#define NSCAN 782               // ceil(MHIST/256)
#define SCOL_CAP 2048           // max edges/bucket in LDS (mean 1024, +32 sigma)

// pool constants
#define PNODES 16               // nodes per wave in pool
#define POOL_BLOCKS 1563        // ceil(100000/16/4)

typedef short v8bf __attribute__((ext_vector_type(8)));
typedef float v4f  __attribute__((ext_vector_type(4)));

__device__ inline ushort f2b(float x) {
    __hip_bfloat16 h = __float2bfloat16(x);
    return *reinterpret_cast<ushort*>(&h);
}
__device__ inline float b2f(ushort u) {
    return __uint_as_float(((unsigned)u) << 16);
}
__device__ inline float blo(unsigned u) { return __uint_as_float(u << 16); }
__device__ inline float bhi(unsigned u) { return __uint_as_float(u & 0xffff0000u); }

// ---------------- prep: both W swizzles + gsum/gcnt zero (one dispatch) ----------
__device__ inline void sw_one(const float* __restrict__ W, ushort* __restrict__ o,
                              int t, int K) {
    const int lane = t & 63, nt = (t >> 6) & 3, ks = t >> 8;
    const int m = lane & 15, quad = lane >> 4;
#pragma unroll
    for (int j = 0; j < 8; ++j) {
        const int kk = ks * 32 + quad * 8 + j;
        const int cc = nt * 16 + m;
        o[t * 8 + j] = f2b(W[kk * 64 + cc]);
    }
}

__global__ __launch_bounds__(256) void prep_kernel(const float* __restrict__ W1l,
                                                   const float* __restrict__ W1r,
                                                   const float* __restrict__ W2l,
                                                   const float* __restrict__ W2r,
                                                   ushort* __restrict__ w1ls,
                                                   ushort* __restrict__ w1rs,
                                                   ushort* __restrict__ w2ls,
                                                   ushort* __restrict__ w2rs,
                                                   float* __restrict__ gz) {
    const int t = blockIdx.x * 256 + threadIdx.x;    // grid 8 -> 2048 threads
    if (t < 1024) {                                  // K=128: (128/32)*4*64 = 1024
        sw_one(W1l, w1ls, t, FF);
        sw_one(W1r, w1rs, t, FF);
    } else if (t < 1536) {                           // K=64: 512
        sw_one(W2l, w2ls, t - 1024, HH);
        sw_one(W2r, w2rs, t - 1024, HH);
    } else {
        for (int i = t - 1536; i < GG * 64 + GG; i += 512) gz[i] = 0.f;
    }
}

// ---------------- dual MFMA GEMM: Yl = X@Wl, Yr = X@Wr (bf16 out) ----------------
template<int K, int TPB, bool AF32>
__global__ __launch_bounds__(256) void gemm_mfma(const void* __restrict__ Xv,
                                                 const ushort* __restrict__ Bl,
                                                 const ushort* __restrict__ Br,
                                                 ushort* __restrict__ Yl,
                                                 ushort* __restrict__ Yr) {
    constexpr int KS = K / 32;
    const int lane  = threadIdx.x & 63;
    const int wave  = threadIdx.x >> 6;
    const int nhalf = wave & 1;
    const int rsub  = wave >> 1;
    const int m = lane & 15, quad = lane >> 4;

    v8bf bl[KS][2], br[KS][2];
#pragma unroll
    for (int ks = 0; ks < KS; ++ks)
#pragma unroll
        for (int nt = 0; nt < 2; ++nt) {
            const int nti = nhalf * 2 + nt;
            bl[ks][nt] = *(const v8bf*)(Bl + ((size_t)(ks * 4 + nti) * 64 + lane) * 8);
            br[ks][nt] = *(const v8bf*)(Br + ((size_t)(ks * 4 + nti) * 64 + lane) * 8);
        }

    for (int it = 0; it < TPB; ++it) {
        const int bt = blockIdx.x * TPB + it;
        const int row0 = bt * 32 + rsub * 16;
        if (row0 >= NN) return;
        const v4f z = {0.f, 0.f, 0.f, 0.f};
        v4f accl[2] = {z, z}, accr[2] = {z, z};
#pragma unroll
        for (int ks = 0; ks < KS; ++ks) {
            v8bf a;
            if (AF32) {
                const float* xrow = (const float*)Xv + (size_t)(row0 + m) * K + quad * 8 + ks * 32;
                const float4 a0 = *(const float4*)(xrow);
                const float4 a1 = *(const float4*)(xrow + 4);
                a[0] = (short)f2b(a0.x); a[1] = (short)f2b(a0.y);
                a[2] = (short)f2b(a0.z); a[3] = (short)f2b(a0.w);
                a[4] = (short)f2b(a1.x); a[5] = (short)f2b(a1.y);
                a[6] = (short)f2b(a1.z); a[7] = (short)f2b(a1.w);
            } else {
                const ushort* xrow = (const ushort*)Xv + (size_t)(row0 + m) * K + quad * 8 + ks * 32;
                a = *(const v8bf*)xrow;
            }
#pragma unroll
            for (int nt = 0; nt < 2; ++nt) {
                accl[nt] = __builtin_amdgcn_mfma_f32_16x16x32_bf16(a, bl[ks][nt], accl[nt], 0, 0, 0);
                accr[nt] = __builtin_amdgcn_mfma_f32_16x16x32_bf16(a, br[ks][nt], accr[nt], 0, 0, 0);
            }
        }
#pragma unroll
        for (int nt = 0; nt < 2; ++nt) {
            const int cc = nhalf * 32 + nt * 16 + m;
#pragma unroll
            for (int r = 0; r < 4; ++r) {
                const size_t off = (size_t)(row0 + quad * 4 + r) * 64 + cc;
                Yl[off] = f2b(accl[nt][r]);
                Yr[off] = f2b(accr[nt][r]);
            }
        }
    }
}

// ---------------- pass A1: per-(block,bucket) histogram (1024 threads) ----------------
__global__ __launch_bounds__(1024) void edge_hist(const int* __restrict__ dst,
                                                  int* __restrict__ hist) {
    __shared__ int h[NB];
    for (int i = threadIdx.x; i < NB; i += 1024) h[i] = 0;
    __syncthreads();
    const int e0 = blockIdx.x * ECHUNK;
    for (int e = e0 + threadIdx.x; e < e0 + ECHUNK; e += 1024)
        atomicAdd(&h[dst[e] >> 6], 1);
    __syncthreads();
    for (int i = threadIdx.x; i < NB; i += 1024)
        hist[i * PBLK + blockIdx.x] = h[i];   // bucket-major for the scan
}

// ---------------- pass A2: scan (block-local prefix; boff folded into consumers) -----
__global__ __launch_bounds__(256) void scan_block(const int* __restrict__ cnt,
                                                  int* __restrict__ rp,
                                                  int* __restrict__ bsum) {
    __shared__ int s[256];
    const int tid = threadIdx.x;
    const int i = blockIdx.x * 256 + tid;
    const int v = (i < MHIST) ? cnt[i] : 0;
    s[tid] = v;
    __syncthreads();
    for (int off = 1; off < 256; off <<= 1) {
        int t = (tid >= off) ? s[tid - off] : 0;
        __syncthreads();
        s[tid] += t;
        __syncthreads();
    }
    if (i < MHIST) rp[i] = s[tid] - v;
    if (tid == 255) bsum[blockIdx.x] = s[255];
}

// scan of NSCAN block sums: 256 threads x 4 elements each
__global__ __launch_bounds__(256) void scan_bsums(const int* __restrict__ bsum,
                                                  int* __restrict__ boff) {
    __shared__ int s[256];
    const int tid = threadIdx.x;
    int v[4];
    int tot = 0;
#pragma unroll
    for (int j = 0; j < 4; ++j) {
        const int idx = tid * 4 + j;
        v[j] = (idx < NSCAN) ? bsum[idx] : 0;
        tot += v[j];
    }
    s[tid] = tot;
    __syncthreads();
    for (int off = 1; off < 256; off <<= 1) {
        int t = (tid >= off) ? s[tid - off] : 0;
        __syncthreads();
        s[tid] += t;
        __syncthreads();
    }
    int run = s[tid] - tot;   // exclusive base for this thread's 4
#pragma unroll
    for (int j = 0; j < 4; ++j) {
        const int idx = tid * 4 + j;
        if (idx < NSCAN) boff[idx] = run;
        run += v[j];
    }
}

// ---------------- pass A3: scatter to exact positions (1024 threads) ----------
__global__ __launch_bounds__(1024) void edge_scatter(const int* __restrict__ src,
                                                     const int* __restrict__ dst,
                                                     const int* __restrict__ goffs,
                                                     const int* __restrict__ boff,
                                                     int* __restrict__ pairs) {
    __shared__ int cur[NB];
    for (int i = threadIdx.x; i < NB; i += 1024) {
        const int idx = i * PBLK + blockIdx.x;
        cur[i] = goffs[idx] + boff[idx >> 8];
    }
    __syncthreads();
    const int e0 = blockIdx.x * ECHUNK;
    for (int e = e0 + threadIdx.x; e < e0 + ECHUNK; e += 1024) {
        const int s = src[e];
        const int d = dst[e];
        const int pos = atomicAdd(&cur[d >> 6], 1);
        pairs[pos] = (s << 6) | (d & (BNODES - 1));
    }
}

// ---------------- pass B: LDS counting-sort + register-gather + fused epilogue -------
__global__ __launch_bounds__(256) void spmm_sorted(const int* __restrict__ goffs,
                                                   const int* __restrict__ boff,
                                                   const int* __restrict__ pairs,
                                                   const ushort* __restrict__ Yl,
                                                   const ushort* __restrict__ Yr,
                                                   const float* __restrict__ bias,
                                                   const float* __restrict__ bng,
                                                   const float* __restrict__ bnb,
                                                   const float* __restrict__ bnm,
                                                   const float* __restrict__ bnv,
                                                   ushort* __restrict__ outp) {
    __shared__ int scol[SCOL_CAP];      // 8 KB: sorted src ids
    __shared__ int deg[BNODES];
    __shared__ int loffs[BNODES];       // inclusive scan of deg
    __shared__ int fill[BNODES];
    const int tid = threadIdx.x;
    const int b = blockIdx.x;

    if (tid < BNODES) { deg[tid] = 0; fill[tid] = 0; }
    __syncthreads();

    const int beg = goffs[b * PBLK] + boff[b >> 1];
    int end = (b == NB - 1) ? NE : goffs[(b + 1) * PBLK] + boff[(b + 1) >> 1];
    if (end - beg > SCOL_CAP) end = beg + SCOL_CAP;

    // phase 1: per-dstLocal degree count (cache pairs in registers for phase 3)
    int pv[8];
    int npv = 0;
    for (int i = beg + tid; i < end; i += 256) {
        const int v = pairs[i];
        pv[npv++] = v;
        atomicAdd(&deg[v & (BNODES - 1)], 1);
    }
    __syncthreads();

    // phase 2: inclusive scan of deg -> loffs
    if (tid < BNODES) loffs[tid] = deg[tid];
    __syncthreads();
    for (int s = 1; s < BNODES; s <<= 1) {
        int v = 0;
        if (tid < BNODES && tid >= s) v = loffs[tid - s];
        __syncthreads();
        if (tid < BNODES) loffs[tid] += v;
        __syncthreads();
    }

    // phase 3: scatter src ids into dst-sorted order (from register cache)
    for (int j = 0; j < npv; ++j) {
        const int v = pv[j];
        const int dl = v & (BNODES - 1);
        const int pos = (loffs[dl] - deg[dl]) + atomicAdd(&fill[dl], 1);
        scol[pos] = v >> 6;
    }
    __syncthreads();

    // phase 4: gather + mean + bias + root + BN + ReLU
    // 8 lanes per node, 8 channels per lane (uint4 = one full 128B row per edge)
    const int wv = tid >> 6, lane = tid & 63;
    const int grp = lane >> 3, subl = lane & 7;

    float biasj[8], scj[8], mj[8], bbj[8];
#pragma unroll
    for (int j = 0; j < 8; ++j) {
        const int ch = subl * 8 + j;
        biasj[j] = bias[ch];
        scj[j] = bng[ch] * rsqrtf(bnv[ch] + BN_EPS);
        mj[j] = bnm[ch];
        bbj[j] = bnb[ch];
    }

    for (int i = 0; i < 2; ++i) {
        const int nl = wv * 16 + i * 8 + grp;
        const int node = b * BNODES + nl;
        if (node >= NN) continue;
        const int dg = deg[nl];
        const int nbeg = loffs[nl] - dg;
        const int nend = nbeg + dg;
        float a[8] = {0.f, 0.f, 0.f, 0.f, 0.f, 0.f, 0.f, 0.f};
        float c[8] = {0.f, 0.f, 0.f, 0.f, 0.f, 0.f, 0.f, 0.f};
        int e = nbeg;
        for (; e + 1 < nend; e += 2) {
            const int s0 = scol[e];
            const int s1 = scol[e + 1];
            const uint4 r0 = *(const uint4*)(Yl + (size_t)s0 * 64 + subl * 8);
            const uint4 r1 = *(const uint4*)(Yl + (size_t)s1 * 64 + subl * 8);
            a[0] += blo(r0.x); a[1] += bhi(r0.x); a[2] += blo(r0.y); a[3] += bhi(r0.y);
            a[4] += blo(r0.z); a[5] += bhi(r0.z); a[6] += blo(r0.w); a[7] += bhi(r0.w);
            c[0] += blo(r1.x); c[1] += bhi(r1.x); c[2] += blo(r1.y); c[3] += bhi(r1.y);
            c[4] += blo(r1.z); c[5] += bhi(r1.z); c[6] += blo(r1.w); c[7] += bhi(r1.w);
        }
        if (e < nend) {
            const int s0 = scol[e];
            const uint4 r0 = *(const uint4*)(Yl + (size_t)s0 * 64 + subl * 8);
            a[0] += blo(r0.x); a[1] += bhi(r0.x); a[2] += blo(r0.y); a[3] += bhi(r0.y);
            a[4] += blo(r0.z); a[5] += bhi(r0.z); a[6] += blo(r0.w); a[7] += bhi(r0.w);
        }
        const float inv = 1.0f / fmaxf((float)dg, 1.0f);
        const uint4 yr = *(const uint4*)(Yr + (size_t)node * 64 + subl * 8);
        float hj[8];
        hj[0] = (a[0] + c[0]) * inv + biasj[0] + blo(yr.x);
        hj[1] = (a[1] + c[1]) * inv + biasj[1] + bhi(yr.x);
        hj[2] = (a[2] + c[2]) * inv + biasj[2] + blo(yr.y);
        hj[3] = (a[3] + c[3]) * inv + biasj[3] + bhi(yr.y);
        hj[4] = (a[4] + c[4]) * inv + biasj[4] + blo(yr.z);
        hj[5] = (a[5] + c[5]) * inv + biasj[5] + bhi(yr.z);
        hj[6] = (a[6] + c[6]) * inv + biasj[6] + blo(yr.w);
        hj[7] = (a[7] + c[7]) * inv + biasj[7] + bhi(yr.w);
        unsigned ow[4];
#pragma unroll
        for (int j = 0; j < 4; ++j) {
            const float o0 = fmaxf((hj[2 * j] - mj[2 * j]) * scj[2 * j] + bbj[2 * j], 0.0f);
            const float o1 = fmaxf((hj[2 * j + 1] - mj[2 * j + 1]) * scj[2 * j + 1] + bbj[2 * j + 1], 0.0f);
            ow[j] = (unsigned)f2b(o0) | ((unsigned)f2b(o1) << 16);
        }
        uint4 o;
        o.x = ow[0]; o.y = ow[1]; o.z = ow[2]; o.w = ow[3];
        *(uint4*)(outp + (size_t)node * 64 + subl * 8) = o;
    }
}

// ---------------- segmented global mean pool: 16 nodes/wave ----------------
__global__ __launch_bounds__(256) void pool_seg(const ushort* __restrict__ h,
                                                const int* __restrict__ batch,
                                                float* __restrict__ gsum,
                                                float* __restrict__ gcnt) {
    const int wave = blockIdx.x * 4 + (threadIdx.x >> 6);
    const int lane = threadIdx.x & 63;
    const int n0 = wave * PNODES;
    if (n0 >= NN) return;
    const int n1 = (n0 + PNODES < NN) ? n0 + PNODES : NN;
    int g = batch[n0];
    float acc = 0.f, c = 0.f;
#pragma unroll 4
    for (int n = n0; n < n1; ++n) {
        const int b = batch[n];
        if (b != g) {
            atomicAdd(&gsum[g * 64 + lane], acc);
            if (lane == 0) atomicAdd(&gcnt[g], c);
            acc = 0.f; c = 0.f; g = b;
        }
        acc += b2f(h[(size_t)n * 64 + lane]);
        c += 1.0f;
    }
    atomicAdd(&gsum[g * 64 + lane], acc);
    if (lane == 0) atomicAdd(&gcnt[g], c);
}

// ---------------- classifier head ----------------
__global__ __launch_bounds__(64) void head_kernel(const float* __restrict__ gsum,
                                                  const float* __restrict__ gcnt,
                                                  const float* __restrict__ Wc1,
                                                  const float* __restrict__ bc1,
                                                  const float* __restrict__ g3,
                                                  const float* __restrict__ b3,
                                                  const float* __restrict__ m3,
                                                  const float* __restrict__ v3,
                                                  const float* __restrict__ Wc2,
                                                  const float* __restrict__ bc2,
                                                  float* __restrict__ out) {
    __shared__ float sg[64];
    __shared__ float st[64];
    __shared__ float sl[10];
    __shared__ float sls;
    const int b = blockIdx.x;
    const int c = threadIdx.x;
    sg[c] = gsum[b * 64 + c] / fmaxf(gcnt[b], 1.0f);
    __syncthreads();
    float acc = bc1[c];
#pragma unroll
    for (int k = 0; k < 64; ++k) acc += sg[k] * Wc1[k * 64 + c];
    const float sc = g3[c] * rsqrtf(v3[c] + BN_EPS);
    st[c] = fmaxf((acc - m3[c]) * sc + b3[c], 0.0f);
    __syncthreads();
    if (c < CC) {
        float lg = bc2[c];
#pragma unroll
        for (int k = 0; k < 64; ++k) lg += st[k] * Wc2[k * CC + c];
        sl[c] = lg;
    }
    __syncthreads();
    if (c == 0) {
        float mx = sl[0];
        for (int i = 1; i < CC; ++i) mx = fmaxf(mx, sl[i]);
        float s = 0.f;
        for (int i = 0; i < CC; ++i) s += expf(sl[i] - mx);
        sls = mx + logf(s);
    }
    __syncthreads();
    if (c < CC) out[b * CC + c] = sl[c] - sls;
}

extern "C" void kernel_launch(void* const* d_in, const int* in_sizes, int n_in,
                              void* d_out, int out_size, void* d_ws, size_t ws_size,
                              hipStream_t stream) {
    const float* x    = (const float*)d_in[0];
    const int*   ei   = (const int*)d_in[1];
    const int*   batch= (const int*)d_in[2];
    const float* W1l  = (const float*)d_in[3];
    const float* W1r  = (const float*)d_in[4];
    const float* b1   = (const float*)d_in[5];
    const float* W2l  = (const float*)d_in[6];
    const float* W2r  = (const float*)d_in[7];
    const float* b2   = (const float*)d_in[8];
    const float* bn1g = (const float*)d_in[9];
    const float* bn1b = (const float*)d_in[10];
    const float* bn1m = (const float*)d_in[11];
    const float* bn1v = (const float*)d_in[12];
    const float* bn2g = (const float*)d_in[13];
    const float* bn2b = (const float*)d_in[14];
    const float* bn2m = (const float*)d_in[15];
    const float* bn2v = (const float*)d_in[16];
    const float* bn3g = (const float*)d_in[17];
    const float* bn3b = (const float*)d_in[18];
    const float* bn3m = (const float*)d_in[19];
    const float* bn3v = (const float*)d_in[20];
    const float* Wc1  = (const float*)d_in[21];
    const float* bc1  = (const float*)d_in[22];
    const float* Wc2  = (const float*)d_in[23];
    const float* bc2  = (const float*)d_in[24];
    float* out = (float*)d_out;

    const int* src = ei;
    const int* dst = ei + NE;

    // workspace layout (all blocks 16B-aligned)
    char* p = (char*)d_ws;
    ushort* yl   = (ushort*)p;                 p += (size_t)NN * 64 * 2;        // 12.8 MB
    ushort* yr   = (ushort*)p;                 p += (size_t)NN * 64 * 2;        // 12.8 MB
    ushort* hbuf = (ushort*)p;                 p += (size_t)NN * 64 * 2;        // 12.8 MB
    int*    pairs= (int*)p;                    p += (size_t)NE * 4;             // 6.4 MB
    int*    hist = (int*)p;                    p += (size_t)MHIST * 4;          // 800 KB
    int*    goffs= (int*)p;                    p += (size_t)MHIST * 4;          // 800 KB
    int*    bsum = (int*)p;                    p += 1024 * 4;
    int*    boff = (int*)p;                    p += 1024 * 4;
    ushort* w1ls = (ushort*)p;                 p += (size_t)FF * 64 * 2;
    ushort* w1rs = (ushort*)p;                 p += (size_t)FF * 64 * 2;
    ushort* w2ls = (ushort*)p;                 p += (size_t)HH * 64 * 2;
    ushort* w2rs = (ushort*)p;                 p += (size_t)HH * 64 * 2;
    float* gsum  = (float*)p;                  p += (size_t)GG * 64 * 4;        // gsum+gcnt
    float* gcnt  = gsum + GG * 64;             p += (size_t)GG * 4;             //  contiguous

    // ---- edge counting sort (once, reused by both layers) ----
    edge_hist<<<PBLK, 1024, 0, stream>>>(dst, hist);
    scan_block<<<NSCAN, 256, 0, stream>>>(hist, goffs, bsum);
    scan_bsums<<<1, 256, 0, stream>>>(bsum, boff);
    edge_scatter<<<PBLK, 1024, 0, stream>>>(src, dst, goffs, boff, pairs);

    // ---- weight swizzles + gsum/gcnt zero ----
    prep_kernel<<<8, 256, 0, stream>>>(W1l, W1r, W2l, W2r, w1ls, w1rs, w2ls, w2rs, gsum);

    // ---- layer 1 ----
    gemm_mfma<FF, 2, true><<<1563, 256, 0, stream>>>((const void*)x, w1ls, w1rs, yl, yr);
    spmm_sorted<<<NB, 256, 0, stream>>>(goffs, boff, pairs, yl, yr, b1,
                                        bn1g, bn1b, bn1m, bn1v, hbuf);

    // ---- layer 2 ----
    gemm_mfma<HH, 2, false><<<1563, 256, 0, stream>>>((const void*)hbuf, w2ls, w2rs, yl, yr);
    spmm_sorted<<<NB, 256, 0, stream>>>(goffs, boff, pairs, yl, yr, b2,
                                        bn2g, bn2b, bn2m, bn2v, hbuf);

    // ---- pool + head ----
    pool_seg<<<POOL_BLOCKS, 256, 0, stream>>>(hbuf, batch, gsum, gcnt);
    head_kernel<<<GG, 64, 0, stream>>>(gsum, gcnt, Wc1, bc1,
                                       bn3g, bn3b, bn3m, bn3v, Wc2, bc2, out);
}